// Round 8
// baseline (918.771 us; speedup 1.0000x reference)
//
#include <hip/hip_runtime.h>
#include <math.h>

// Problem constants
#define BB 4
#define CC 192
#define HH 96
#define WW 96
#define PP (HH*WW)          // 9216
#define C2 (2*CC)           // 384

typedef unsigned short ushort_t;
typedef __bf16 bf16_t;
typedef bf16_t bf16x8 __attribute__((ext_vector_type(8)));
typedef float floatx16 __attribute__((ext_vector_type(16)));

__device__ __forceinline__ float sigmoidf_(float x) { return 1.f / (1.f + expf(-x)); }

__device__ __forceinline__ ushort_t f2bf(float f) {
    unsigned u = __builtin_bit_cast(unsigned, f);
    unsigned r = (u + 0x7fffu + ((u >> 16) & 1u)) >> 16;
    return (ushort_t)r;
}
__device__ __forceinline__ float bflo(unsigned u) {
    return __builtin_bit_cast(float, u << 16);
}
__device__ __forceinline__ float bfhi(unsigned u) {
    return __builtin_bit_cast(float, u & 0xffff0000u);
}

// ---------------- conv 1x1 ----------------------------------------------------------------
// unroll 8: 8 stride-PP float4 loads in flight (R7: neutral vs 4, kept).
template<int CIN, bool RELU, bool HASB>
__global__ __launch_bounds__(256) void conv1x1_kernel(
    const float* __restrict__ in, const float* __restrict__ w,
    const float* __restrict__ bias, float* __restrict__ out,
    long in_bs, long out_bs)
{
    int b = blockIdx.z;
    int co0 = blockIdx.y * 16;
    int p = blockIdx.x * 1024 + threadIdx.x * 4;
    const float* ip = in + (long)b * in_bs + p;
    float4 acc[16];
#pragma unroll
    for (int j = 0; j < 16; ++j) acc[j] = make_float4(0.f, 0.f, 0.f, 0.f);
#pragma unroll 8
    for (int ci = 0; ci < CIN; ++ci) {
        float4 xv = *(const float4*)(ip + (long)ci * PP);
        if (RELU) {
            xv.x = fmaxf(xv.x, 0.f); xv.y = fmaxf(xv.y, 0.f);
            xv.z = fmaxf(xv.z, 0.f); xv.w = fmaxf(xv.w, 0.f);
        }
#pragma unroll
        for (int j = 0; j < 16; ++j) {
            float wv = w[(long)(co0 + j) * CIN + ci];
            acc[j].x += wv * xv.x; acc[j].y += wv * xv.y;
            acc[j].z += wv * xv.z; acc[j].w += wv * xv.w;
        }
    }
#pragma unroll
    for (int j = 0; j < 16; ++j) {
        if (HASB) {
            float bb = bias[co0 + j];
            acc[j].x += bb; acc[j].y += bb; acc[j].z += bb; acc[j].w += bb;
        }
        *(float4*)(out + (long)b * out_bs + (long)(co0 + j) * PP + p) = acc[j];
    }
}

// ---------------- grouped conv 3x3, groups=192, 2in->2out, pad 1, 4px/thread -------------
__global__ __launch_bounds__(256) void dwconv_kernel(
    const float* __restrict__ in, const float* __restrict__ w, float* __restrict__ out)
{
    int b = blockIdx.z, co = blockIdx.y;
    int p = (blockIdx.x * 256 + threadIdx.x) * 4;
    int oy = p / WW, ox = p - oy * WW;
    int g = co >> 1;
    const float* w18 = w + (long)co * 18;
    float a0 = 0.f, a1 = 0.f, a2 = 0.f, a3 = 0.f;
#pragma unroll
    for (int i = 0; i < 2; ++i) {
        const float* ipl = in + ((long)(b * C2 + 2 * g + i)) * PP;
#pragma unroll
        for (int ky = 0; ky < 3; ++ky) {
            int yy = oy - 1 + ky;
            if ((unsigned)yy < (unsigned)HH) {
                const float* row = ipl + yy * WW;
                float v[6];
#pragma unroll
                for (int j = 0; j < 6; ++j) {
                    int xx = ox - 1 + j;
                    v[j] = ((unsigned)xx < (unsigned)WW) ? row[xx] : 0.f;
                }
#pragma unroll
                for (int kx = 0; kx < 3; ++kx) {
                    float wv = w18[i * 9 + ky * 3 + kx];
                    a0 += wv * v[kx]; a1 += wv * v[kx + 1];
                    a2 += wv * v[kx + 2]; a3 += wv * v[kx + 3];
                }
            }
        }
    }
    float4 r = make_float4(a0, a1, a2, a3);
    *(float4*)(out + ((long)(b * C2 + co)) * PP + p) = r;
}

// ---------------- fused avgpool 2x2 + bf16 + transpose: poolb[b][px48][ci] ---------------
__global__ __launch_bounds__(256) void avgpool_bf16_kernel(
    const float* __restrict__ qkv2, const float* __restrict__ y, ushort_t* __restrict__ poolb)
{
    __shared__ __align__(16) ushort_t sT[64 * 392];
    int b = blockIdx.y;
    int px0 = blockIdx.x * 64;
    int t = threadIdx.x;
    for (int idx = t; idx < 384 * 64; idx += 256) {
        int ci = idx >> 6, px = idx & 63;
        int p = px0 + px;
        int oy = p / 48, ox = p - oy * 48;
        const float* base = (ci < CC) ? qkv2 + ((long)(b * C2 + ci)) * PP
                                      : y + ((long)(b * CC + ci - CC)) * PP;
        const float* ipl = base + (oy * 2) * WW + ox * 2;
        float v = 0.25f * (ipl[0] + ipl[1] + ipl[WW] + ipl[WW + 1]);
        sT[px * 392 + ci] = f2bf(v);
    }
    __syncthreads();
    int px = t >> 2, qr = t & 3;
    ushort_t* dst = poolb + ((long)b * 2304 + px0 + px) * C2 + qr * 96;
    const ushort_t* srcl = sT + px * 392 + qr * 96;
#pragma unroll
    for (int k = 0; k < 96; k += 8)
        *(uint4*)(dst + k) = *(const uint4*)(srcl + k);
}

// ---------------- packed weight prep: wpk[((tap*NG+cg)*24+chunk)*64 + n*2+q][8] -----------
template<int NG>
__global__ __launch_bounds__(256) void prep_wpk_kernel(
    const float* __restrict__ w, ushort_t* __restrict__ wpk, int coutv)
{
    int i = blockIdx.x * 256 + threadIdx.x;
    int j = i & 7;
    int q = (i >> 3) & 1;
    int n = (i >> 4) & 31;
    int r = i >> 9;
    int chunk = r % 24;
    int r2 = r / 24;
    int cg = r2 % NG;
    int tap = r2 / NG;
    int co = cg * 32 + n;
    int ci = chunk * 16 + q * 8 + j;
    wpk[i] = (co < coutv) ? f2bf(w[((long)co * 384 + ci) * 9 + tap]) : (ushort_t)0;
}

// ---------------- conv48 MFMA: valid 3x3 48->46, double-buffered input staging -----------
// cell stride 24 ushorts (48 B): b128 LDS reads/writes, bank-tiling {0,12,24,...} -> 0 conflicts
__global__ __launch_bounds__(256) void conv48_mfma_kernel(
    const ushort_t* __restrict__ poolb, const ushort_t* __restrict__ wpk,
    float* __restrict__ out)
{
    __shared__ __align__(16) ushort_t sB[2][288 * 24];
    int b = blockIdx.z;
    int co0 = blockIdx.y * 128;
    int cgb = blockIdx.y * 4;
    int y0 = blockIdx.x * 4;
    int t = threadIdx.x;
    int w = t >> 6, lane = t & 63;
    int n = lane & 31, q = lane >> 5;
    int wc = w & 1, wn = w >> 1;
    const uint4* wq = (const uint4*)wpk;

    int pidx[3], rr[3], ccx[3];
#pragma unroll
    for (int xg = 0; xg < 3; ++xg) {
        int p = (wn * 3 + xg) * 32 + n;
        int pc = min(p, 183);
        pidx[xg] = p;
        rr[xg] = pc / 46;
        ccx[xg] = pc - rr[xg] * 46;
    }

    floatx16 acc[2][3];
#pragma unroll
    for (int a = 0; a < 2; ++a)
#pragma unroll
        for (int xg = 0; xg < 3; ++xg) acc[a][xg] = (floatx16)(0.f);

    const ushort_t* poolb_b = poolb + (long)b * 2304 * C2;

    bool sok[2]; long gof[2]; int lof[2]; bool sval[2];
#pragma unroll
    for (int s = 0; s < 2; ++s) {
        int c = t + s * 256;
        sval[s] = (c < 288);
        int cc = min(c, 287);
        int r = cc / 48, col = cc - r * 48;
        int iy = y0 + r;
        sok[s] = (iy < 48);
        gof[s] = ((long)(min(iy, 47) * 48 + col)) * C2;
        lof[s] = cc * 24;
    }
    uint4 sv[2][2];

#define C48_ISSUE(mm)                                                        \
    {                                                                        \
        int ci0 = (mm) * 16;                                                 \
        _Pragma("unroll")                                                    \
        for (int s = 0; s < 2; ++s) {                                        \
            if (sval[s] && sok[s]) {                                         \
                const ushort_t* sp = poolb_b + gof[s] + ci0;                 \
                sv[s][0] = *(const uint4*)(sp);                              \
                sv[s][1] = *(const uint4*)(sp + 8);                          \
            } else {                                                         \
                sv[s][0] = make_uint4(0u,0u,0u,0u);                          \
                sv[s][1] = make_uint4(0u,0u,0u,0u);                          \
            }                                                                \
        }                                                                    \
    }
#define C48_COMMIT(buf)                                                      \
    {                                                                        \
        _Pragma("unroll")                                                    \
        for (int s = 0; s < 2; ++s) {                                        \
            if (sval[s]) {                                                   \
                ushort_t* d = sB[buf] + lof[s];                              \
                *(uint4*)(d + 0) = sv[s][0];                                 \
                *(uint4*)(d + 8) = sv[s][1];                                 \
            }                                                                \
        }                                                                    \
    }

    C48_ISSUE(0); C48_COMMIT(0);
    __syncthreads();

    for (int m = 0; m < 24; ++m) {
        int cur = m & 1;
        if (m < 23) C48_ISSUE(m + 1);
#pragma unroll
        for (int ky = 0; ky < 3; ++ky) {
            uint4 wv[6];
#pragma unroll
            for (int kx = 0; kx < 3; ++kx)
#pragma unroll
                for (int a = 0; a < 2; ++a)
                    wv[kx * 2 + a] = wq[(long)(((ky * 3 + kx) * 12 + cgb + wc * 2 + a) * 24 + m) * 64 + lane];
#pragma unroll
            for (int kx = 0; kx < 3; ++kx) {
                bf16x8 af[2], bfm[3];
#pragma unroll
                for (int a = 0; a < 2; ++a)
                    af[a] = __builtin_bit_cast(bf16x8, wv[kx * 2 + a]);
#pragma unroll
                for (int xg = 0; xg < 3; ++xg) {
                    int cell = (rr[xg] + ky) * 48 + ccx[xg] + kx;
                    uint4 bv = *(const uint4*)(sB[cur] + cell * 24 + q * 8);
                    bfm[xg] = __builtin_bit_cast(bf16x8, bv);
                }
#pragma unroll
                for (int a = 0; a < 2; ++a)
#pragma unroll
                    for (int xg = 0; xg < 3; ++xg)
                        acc[a][xg] = __builtin_amdgcn_mfma_f32_32x32x16_bf16(
                            af[a], bfm[xg], acc[a][xg], 0, 0, 0);
            }
        }
        if (m < 23) C48_COMMIT(cur ^ 1);
        __syncthreads();
    }

#pragma unroll
    for (int a = 0; a < 2; ++a) {
        int cobase = co0 + (wc * 2 + a) * 32;
#pragma unroll
        for (int xg = 0; xg < 3; ++xg) {
            int oy = y0 + rr[xg], ox = ccx[xg];
            if (pidx[xg] >= 184 || oy >= 46) continue;
#pragma unroll
            for (int r = 0; r < 16; ++r) {
                int row = (r & 3) + 8 * (r >> 2) + 4 * q;
                out[((long)(b * C2 + cobase + row)) * 2116 + oy * 46 + ox] = acc[a][xg][r];
            }
        }
    }
}

// ---------------- cvt_cat: catb[b][px][ci] bf16 from cat(q=qkv2[0:192], y) ----------------
__global__ __launch_bounds__(256) void cvt_cat_kernel(
    const float* __restrict__ qkv2, const float* __restrict__ y, ushort_t* __restrict__ catb)
{
    __shared__ __align__(16) ushort_t sT[64 * 392];
    int b = blockIdx.y;
    int px0 = blockIdx.x * 64;
    int t = threadIdx.x;
    for (int idx = t; idx < 384 * 64; idx += 256) {
        int ci = idx >> 6, px = idx & 63;
        const float* src = (ci < CC) ? qkv2 + ((long)(b * C2 + ci)) * PP
                                     : y + ((long)(b * CC + ci - CC)) * PP;
        sT[px * 392 + ci] = f2bf(src[px0 + px]);
    }
    __syncthreads();
    int px = t >> 2, qr = t & 3;
    ushort_t* dst = catb + ((long)b * PP + px0 + px) * C2 + qr * 96;
    const ushort_t* srcl = sT + px * 392 + qr * 96;
#pragma unroll
    for (int k = 0; k < 96; k += 8)
        *(uint4*)(dst + k) = *(const uint4*)(srcl + k);
}

// ---------------- conv96 MFMA: 1 row/block, 1152 blocks, wave = 32co x 96px --------------
// grid (96, 3, B); block 256 (4 waves). LDS: 3 rows x 98 cols, double-buffered.
// v4 = v3 (weight-loads-first + XCD stripe swizzle) + b128 LDS (cell stride 24 ushorts).
__global__ __launch_bounds__(256) void conv96_mfma_kernel(
    const ushort_t* __restrict__ catb, const ushort_t* __restrict__ wpk,
    const float* __restrict__ qkv2, const float* __restrict__ yy,
    const float* __restrict__ k2out, ushort_t* __restrict__ scb)
{
    __shared__ __align__(16) ushort_t sB[2][294 * 24];
    int b = blockIdx.z;
    int co0 = blockIdx.y * 128;
    int cgb = blockIdx.y * 4;
    int bx = blockIdx.x;
    int yl = (bx & 7) * 12 + (bx >> 3);   // XCD stripe swizzle (bijective on [0,96))
    int t = threadIdx.x;
    int w = t >> 6, lane = t & 63;
    int n = lane & 31, q = lane >> 5;
    const uint4* wq = (const uint4*)wpk;

    floatx16 acc[3];
#pragma unroll
    for (int xg = 0; xg < 3; ++xg) acc[xg] = (floatx16)(0.f);

    const ushort_t* catb_b = catb + (long)b * PP * C2;

    // staging geometry: 294 cells = 3 rows (yl-1..yl+1) x 98 cols (x=-1..96)
    bool sok[2]; long gof[2]; int lof[2]; bool sval[2];
#pragma unroll
    for (int s = 0; s < 2; ++s) {
        int c = t + s * 256;
        sval[s] = (c < 294);
        int cc = min(c, 293);
        int r = cc / 98, col = cc - r * 98;
        int iy = yl - 1 + r, ix = col - 1;
        sok[s] = (iy >= 0 && iy < HH && ix >= 0 && ix < WW);
        gof[s] = ((long)(min(max(iy, 0), HH - 1) * WW + min(max(ix, 0), WW - 1))) * C2;
        lof[s] = cc * 24;
    }
    uint4 sv[2][2];

#define C96_ISSUE(mm)                                                        \
    {                                                                        \
        int ci0 = (mm) * 16;                                                 \
        _Pragma("unroll")                                                    \
        for (int s = 0; s < 2; ++s) {                                        \
            if (sval[s] && sok[s]) {                                         \
                const ushort_t* sp = catb_b + gof[s] + ci0;                  \
                sv[s][0] = *(const uint4*)(sp);                              \
                sv[s][1] = *(const uint4*)(sp + 8);                          \
            } else {                                                         \
                sv[s][0] = make_uint4(0u,0u,0u,0u);                          \
                sv[s][1] = make_uint4(0u,0u,0u,0u);                          \
            }                                                                \
        }                                                                    \
    }
#define C96_COMMIT(buf)                                                      \
    {                                                                        \
        _Pragma("unroll")                                                    \
        for (int s = 0; s < 2; ++s) {                                        \
            if (sval[s]) {                                                   \
                ushort_t* d = sB[buf] + lof[s];                              \
                *(uint4*)(d + 0) = sv[s][0];                                 \
                *(uint4*)(d + 8) = sv[s][1];                                 \
            }                                                                \
        }                                                                    \
    }

    C96_ISSUE(0); C96_COMMIT(0);
    __syncthreads();

    for (int m = 0; m < 24; ++m) {
        int cur = m & 1;
        // weight fragments FIRST (before staging issue): the MFMA's weight-wait
        // then leaves the staging loads in flight (vmcnt FIFO order).
        uint4 wv[9];
#pragma unroll
        for (int tap = 0; tap < 9; ++tap)
            wv[tap] = wq[(long)((tap * 12 + cgb + w) * 24 + m) * 64 + lane];
        if (m < 23) C96_ISSUE(m + 1);
#pragma unroll
        for (int ky = 0; ky < 3; ++ky) {
#pragma unroll
            for (int kx = 0; kx < 3; ++kx) {
                bf16x8 af = __builtin_bit_cast(bf16x8, wv[ky * 3 + kx]);
#pragma unroll
                for (int xg = 0; xg < 3; ++xg) {
                    int cell = ky * 98 + xg * 32 + n + kx;
                    uint4 bv = *(const uint4*)(sB[cur] + cell * 24 + q * 8);
                    bf16x8 bfm = __builtin_bit_cast(bf16x8, bv);
                    acc[xg] = __builtin_amdgcn_mfma_f32_32x32x16_bf16(af, bfm, acc[xg], 0, 0, 0);
                }
            }
        }
        if (m < 23) C96_COMMIT(cur ^ 1);
        __syncthreads();
    }

    // epilogue: scb[b][px][co] = bf16( acc * sigmoid(cat + nearest(k2out)) )
    int iy46 = (yl * 46) / 96;
    int cobase = co0 + w * 32;
#pragma unroll
    for (int xg = 0; xg < 3; ++xg) {
        int x = xg * 32 + n;
        int ix46 = (x * 46) / 96;
        ushort_t* dst = scb + ((long)(b * PP + yl * WW + x)) * C2;
#pragma unroll
        for (int g = 0; g < 4; ++g) {
            int cog = cobase + 8 * g + 4 * q;
            ushort_t pk[4];
#pragma unroll
            for (int j = 0; j < 4; ++j) {
                int co = cog + j;
                const float* gsrc = (co < CC) ? qkv2 + ((long)(b * C2 + co)) * PP
                                              : yy + ((long)(b * CC + co - CC)) * PP;
                float kv = k2out[((long)(b * C2 + co)) * 2116 + iy46 * 46 + ix46];
                float gg = gsrc[yl * WW + x] + kv;
                pk[j] = f2bf(acc[xg][4 * g + j] * sigmoidf_(gg));
            }
            *(uint2*)(dst + cog) = *(uint2*)pk;
        }
    }
}

// ---------------- k4 MFMA: offs = conv3x3(scb), M=32 pad, double-buffered ----------------
__global__ __launch_bounds__(384) void k4_mfma_kernel(
    const ushort_t* __restrict__ scb, const ushort_t* __restrict__ wpk4,
    float* __restrict__ out)
{
    __shared__ __align__(16) ushort_t sB[2][392 * 24];
    int b = blockIdx.y;
    int y0 = blockIdx.x * 2;
    int t = threadIdx.x;
    int w = t / 64, lane = t & 63;
    int n = lane & 31, q = lane >> 5;
    int wr = w / 3, xg = w - wr * 3;
    const uint4* wq = (const uint4*)wpk4;

    floatx16 acc = (floatx16)(0.f);
    const ushort_t* scb_b = scb + (long)b * PP * C2;

    bool sok[2]; long gof[2]; int lof[2]; bool sval[2];
#pragma unroll
    for (int s = 0; s < 2; ++s) {
        int c = t + s * 384;
        sval[s] = (c < 392);
        int cc = min(c, 391);
        int r = cc / 98, col = cc - r * 98;
        int iy = y0 - 1 + r, ix = col - 1;
        sok[s] = (iy >= 0 && iy < HH && ix >= 0 && ix < WW);
        gof[s] = ((long)(min(max(iy, 0), HH - 1) * WW + min(max(ix, 0), WW - 1))) * C2;
        lof[s] = cc * 24;
    }
    uint4 sv[2][2];

#define K4_ISSUE(mm)                                                         \
    {                                                                        \
        int ci0 = (mm) * 16;                                                 \
        _Pragma("unroll")                                                    \
        for (int s = 0; s < 2; ++s) {                                        \
            if (sval[s] && sok[s]) {                                         \
                const ushort_t* sp = scb_b + gof[s] + ci0;                   \
                sv[s][0] = *(const uint4*)(sp);                              \
                sv[s][1] = *(const uint4*)(sp + 8);                          \
            } else {                                                         \
                sv[s][0] = make_uint4(0u,0u,0u,0u);                          \
                sv[s][1] = make_uint4(0u,0u,0u,0u);                          \
            }                                                                \
        }                                                                    \
    }
#define K4_COMMIT(buf)                                                       \
    {                                                                        \
        _Pragma("unroll")                                                    \
        for (int s = 0; s < 2; ++s) {                                        \
            if (sval[s]) {                                                   \
                ushort_t* d = sB[buf] + lof[s];                              \
                *(uint4*)(d + 0) = sv[s][0];                                 \
                *(uint4*)(d + 8) = sv[s][1];                                 \
            }                                                                \
        }                                                                    \
    }

    K4_ISSUE(0); K4_COMMIT(0);
    __syncthreads();

    for (int m = 0; m < 24; ++m) {
        int cur = m & 1;
        if (m < 23) K4_ISSUE(m + 1);
#pragma unroll
        for (int ky = 0; ky < 3; ++ky) {
            uint4 wv[3];
#pragma unroll
            for (int kx = 0; kx < 3; ++kx)
                wv[kx] = wq[(long)(((ky * 3 + kx) * 24) + m) * 64 + lane];
#pragma unroll
            for (int kx = 0; kx < 3; ++kx) {
                bf16x8 af = __builtin_bit_cast(bf16x8, wv[kx]);
                int col = xg * 32 + n + kx;
                uint4 bv = *(const uint4*)(sB[cur] + ((wr + ky) * 98 + col) * 24 + q * 8);
                bf16x8 bf = __builtin_bit_cast(bf16x8, bv);
                acc = __builtin_amdgcn_mfma_f32_32x32x16_bf16(af, bf, acc, 0, 0, 0);
            }
        }
        if (m < 23) K4_COMMIT(cur ^ 1);
        __syncthreads();
    }

    int yl = y0 + wr;
    int x = xg * 32 + n;
#pragma unroll
    for (int r = 0; r < 16; ++r) {
        int row = (r & 3) + 8 * (r >> 2) + 4 * q;
        if (row < 18)
            out[((long)(b * 18 + row)) * PP + yl * WW + x] = acc[r];
    }
}

// ---------------- deformable conv v3: 8x16 tiles, 128 threads, 2304 blocks ---------------
// Body is byte-identical to the r3 local optimum; only tile GEOMETRY changes.
// r7 counters: grid 1152 = 4.5 blocks/CU (grid-capped, occ 37%). Halving the tile doubles
// blocks (9/CU) and shrinks LDS to 14.8 KB -> ~18 resident waves/CU (1.5x).
#define DWY 14
#define DWX 22
__global__ __launch_bounds__(128) void deform_kernel(
    const ushort_t* __restrict__ catb, const float* __restrict__ offs,
    const float* __restrict__ w, const float* __restrict__ bias, float* __restrict__ out)
{
    __shared__ __align__(16) ushort_t sQ[DWY * DWX * 24];
    int b = blockIdx.z, g = blockIdx.y;
    int tile = blockIdx.x;
    int ty0 = (tile / 6) * 8, tx0 = (tile % 6) * 16;
    int wy0 = ty0 - 3, wx0 = tx0 - 3;
    int t = threadIdx.x;
    int oy = ty0 + (t >> 4), ox = tx0 + (t & 15);
    int p = oy * WW + ox;

    const ushort_t* cb = catb + (long)b * PP * C2 + g * 24;
    for (int idx = t; idx < DWY * DWX * 3; idx += 128) {
        int cell = idx / 3, part = idx - cell * 3;
        int sy = cell / DWX, sx = cell - sy * DWX;
        int syc = min(max(wy0 + sy, 0), HH - 1);
        int sxc = min(max(wx0 + sx, 0), WW - 1);
        uint4 v = *(const uint4*)(cb + ((long)(syc * WW + sxc)) * C2 + part * 8);
        *(uint4*)(sQ + cell * 24 + part * 8) = v;
    }
    __syncthreads();

    const float* ob = offs + (long)b * 18 * PP;
    float acc[24];
#pragma unroll
    for (int o = 0; o < 24; ++o) acc[o] = 0.f;

    for (int k = 0; k < 9; ++k) {
        float dy = ob[(2 * k) * PP + p];
        float dx = ob[(2 * k + 1) * PP + p];
        float mk = sigmoidf_(ob[k * PP + p]);
        float py = dy + (float)(oy - 1 + k / 3);
        float px = dx + (float)(ox - 1 + (k % 3));
        float fy = floorf(py), fx = floorf(px);
        int y0 = (int)fy, x0 = (int)fx;
        float ly = py - fy, lx = px - fx;
        float w00 = (1.f - ly) * (1.f - lx), w01 = (1.f - ly) * lx;
        float w10 = ly * (1.f - lx), w11 = ly * lx;
        bool vy0 = (y0 >= 0 && y0 <= HH - 1), vy1 = (y0 + 1 <= HH - 1) && (y0 + 1 >= 0);
        bool vx0 = (x0 >= 0 && x0 <= WW - 1), vx1 = (x0 + 1 <= WW - 1) && (x0 + 1 >= 0);
        w00 = (vy0 && vx0) ? w00 * mk : 0.f;
        w01 = (vy0 && vx1) ? w01 * mk : 0.f;
        w10 = (vy1 && vx0) ? w10 * mk : 0.f;
        w11 = (vy1 && vx1) ? w11 * mk : 0.f;
        float vals[24];
        bool inwin = (y0 >= wy0) && (y0 - wy0 <= DWY - 2) && (x0 >= wx0) && (x0 - wx0 <= DWX - 2);
        if (inwin) {
            int c00 = (y0 - wy0) * DWX + (x0 - wx0);
            const ushort_t* s00 = sQ + c00 * 24;
#pragma unroll
            for (int part = 0; part < 3; ++part) {
                uint4 A = *(const uint4*)(s00 + part * 8);
                uint4 Bv = *(const uint4*)(s00 + 24 + part * 8);
                uint4 Cv = *(const uint4*)(s00 + DWX * 24 + part * 8);
                uint4 Dv = *(const uint4*)(s00 + DWX * 24 + 24 + part * 8);
                const unsigned* au = (const unsigned*)&A;
                const unsigned* bu = (const unsigned*)&Bv;
                const unsigned* cu = (const unsigned*)&Cv;
                const unsigned* du = (const unsigned*)&Dv;
#pragma unroll
                for (int u = 0; u < 4; ++u) {
                    int ci = part * 8 + u * 2;
                    vals[ci]     = w00 * bflo(au[u]) + w01 * bflo(bu[u])
                                 + w10 * bflo(cu[u]) + w11 * bflo(du[u]);
                    vals[ci + 1] = w00 * bfhi(au[u]) + w01 * bfhi(bu[u])
                                 + w10 * bfhi(cu[u]) + w11 * bfhi(du[u]);
                }
            }
        } else {
            int y0c = min(max(y0, 0), HH - 1), y1c = min(max(y0 + 1, 0), HH - 1);
            int x0c = min(max(x0, 0), WW - 1), x1c = min(max(x0 + 1, 0), WW - 1);
            const ushort_t* p00 = cb + ((long)(y0c * WW + x0c)) * C2;
            const ushort_t* p01 = cb + ((long)(y0c * WW + x1c)) * C2;
            const ushort_t* p10 = cb + ((long)(y1c * WW + x0c)) * C2;
            const ushort_t* p11 = cb + ((long)(y1c * WW + x1c)) * C2;
#pragma unroll
            for (int part = 0; part < 3; ++part) {
                uint4 A = *(const uint4*)(p00 + part * 8);
                uint4 Bv = *(const uint4*)(p01 + part * 8);
                uint4 Cv = *(const uint4*)(p10 + part * 8);
                uint4 Dv = *(const uint4*)(p11 + part * 8);
                const unsigned* au = (const unsigned*)&A;
                const unsigned* bu = (const unsigned*)&Bv;
                const unsigned* cu = (const unsigned*)&Cv;
                const unsigned* du = (const unsigned*)&Dv;
#pragma unroll
                for (int u = 0; u < 4; ++u) {
                    int ci = part * 8 + u * 2;
                    vals[ci]     = w00 * bflo(au[u]) + w01 * bflo(bu[u])
                                 + w10 * bflo(cu[u]) + w11 * bflo(du[u]);
                    vals[ci + 1] = w00 * bfhi(au[u]) + w01 * bfhi(bu[u])
                                 + w10 * bfhi(cu[u]) + w11 * bfhi(du[u]);
                }
            }
        }
        const float* wg = w + (long)g * 24 * 216 + k;
#pragma unroll
        for (int o = 0; o < 24; ++o) {
            const float* wr = wg + (long)o * 216;
            float s = acc[o];
#pragma unroll
            for (int ci = 0; ci < 24; ++ci) s += wr[ci * 9] * vals[ci];
            acc[o] = s;
        }
    }
#pragma unroll
    for (int o = 0; o < 24; ++o)
        out[((long)(b * CC + g * 24 + o)) * PP + p] = acc[o] + bias[g * 24 + o];
}

// ---------------- L2 norms of q and k rows -----------------------------------------------
__global__ __launch_bounds__(256) void norm_kernel(
    const float* __restrict__ q, const float* __restrict__ kb, float* __restrict__ norms)
{
    int c = blockIdx.x, b = blockIdx.y, which = blockIdx.z;
    const float* src = (which == 0) ? q + ((long)(b * C2 + c)) * PP
                                    : kb + ((long)(b * CC + c)) * PP;
    float s = 0.f;
    for (int n = threadIdx.x * 4; n < PP; n += 1024) {
        float4 v = *(const float4*)(src + n);
        s += v.x * v.x + v.y * v.y + v.z * v.z + v.w * v.w;
    }
    __shared__ float red[256];
    red[threadIdx.x] = s;
    __syncthreads();
    for (int st = 128; st > 0; st >>= 1) {
        if (threadIdx.x < st) red[threadIdx.x] += red[threadIdx.x + st];
        __syncthreads();
    }
    if (threadIdx.x == 0)
        norms[((long)which * BB + b) * CC + c] = fmaxf(sqrtf(red[0]), 1e-12f);
}

// ---------------- attention stage A: partial 24x24 dot blocks over 512-px slices ---------
// grid (18, 8, B), block 192 (3 waves). Each wave owns 3 of nine 8x8 (c,d) tiles.
// q,k each read ONCE from global (56 MB total vs ~700 MB for the per-c re-read version).
__global__ __launch_bounds__(192) void attn_part_kernel(
    const float* __restrict__ q, const float* __restrict__ kb, float* __restrict__ part)
{
    __shared__ __align__(16) float sQ[24 * 260];   // 260-pad: row starts at bank 4*r -> 0 conflicts
    __shared__ __align__(16) float sK[24 * 260];
    int slice = blockIdx.x, h = blockIdx.y, b = blockIdx.z;
    int t = threadIdx.x;
    int w = t >> 6, lane = t & 63;
    int a_ = lane >> 3, b_ = lane & 7;
    const float* qbase = q + ((long)(b * C2) + h * 24) * PP;
    const float* kbase = kb + ((long)(b * CC) + h * 24) * PP;

    float4 acc[3];
#pragma unroll
    for (int i = 0; i < 3; ++i) acc[i] = make_float4(0.f, 0.f, 0.f, 0.f);

    for (int sc = 0; sc < 2; ++sc) {
        int n0 = slice * 512 + sc * 256;
        for (int i = t; i < 1536; i += 192) {
            int r = i >> 6, c4 = i & 63;
            *(float4*)(sQ + r * 260 + c4 * 4) =
                *(const float4*)(qbase + (long)r * PP + n0 + c4 * 4);
            *(float4*)(sK + r * 260 + c4 * 4) =
                *(const float4*)(kbase + (long)r * PP + n0 + c4 * 4);
        }
        __syncthreads();
#pragma unroll
        for (int t3 = 0; t3 < 3; ++t3) {
            int tile = w * 3 + t3;
            const float* qr = sQ + ((tile / 3) * 8 + a_) * 260;
            const float* kr = sK + ((tile % 3) * 8 + b_) * 260;
            float4 s = acc[t3];
#pragma unroll 8
            for (int p4 = 0; p4 < 64; ++p4) {
                float4 qv = *(const float4*)(qr + p4 * 4);
                float4 kv = *(const float4*)(kr + p4 * 4);
                s.x += qv.x * kv.x; s.y += qv.y * kv.y;
                s.z += qv.z * kv.z; s.w += qv.w * kv.w;
            }
            acc[t3] = s;
        }
        __syncthreads();
    }
#pragma unroll
    for (int t3 = 0; t3 < 3; ++t3) {
        int tile = w * 3 + t3;
        int c = (tile / 3) * 8 + a_;
        int d = (tile % 3) * 8 + b_;
        float s = acc[t3].x + acc[t3].y + acc[t3].z + acc[t3].w;
        part[(((long)(b * 8 + h) * 18) + slice) * 576 + c * 24 + d] = s;
    }
}

// ---------------- attention stage B: reduce slices + normalize + softmax -----------------
__global__ __launch_bounds__(256) void attn_reduce_kernel(
    const float* __restrict__ part, const float* __restrict__ norms,
    const float* __restrict__ temp, float* __restrict__ attn)
{
    __shared__ float L[576];
    __shared__ float rmx[24], rsm[24];
    int h = blockIdx.x, b = blockIdx.y;
    int t = threadIdx.x;
    const float* pb = part + ((long)(b * 8 + h) * 18) * 576;
    float tmp = temp[h];
    for (int pid = t; pid < 576; pid += 256) {
        float s = 0.f;
#pragma unroll
        for (int sl = 0; sl < 18; ++sl) s += pb[sl * 576 + pid];
        int c = pid / 24, d = pid - c * 24;
        float nq = norms[(long)b * CC + h * 24 + c];
        float nk = norms[(long)(BB + b) * CC + h * 24 + d];
        L[pid] = s / (nq * nk) * tmp;
    }
    __syncthreads();
    if (t < 24) {
        float mx = -3.4e38f;
#pragma unroll
        for (int j = 0; j < 24; ++j) mx = fmaxf(mx, L[t * 24 + j]);
        float sm = 0.f;
#pragma unroll
        for (int j = 0; j < 24; ++j) sm += expf(L[t * 24 + j] - mx);
        rmx[t] = mx; rsm[t] = 1.f / sm;
    }
    __syncthreads();
    for (int pid = t; pid < 576; pid += 256) {
        int c = pid / 24;
        attn[((long)(b * 8 + h)) * 576 + pid] = expf(L[pid] - rmx[c]) * rsm[c];
    }
}

// ---------------- attn @ v: block per (slice, h, b); v read ONCE ------------------------
__global__ __launch_bounds__(128) void attn_apply_kernel(
    const float* __restrict__ attn, const float* __restrict__ qkv2, float* __restrict__ out)
{
    __shared__ float sA[576];
    int slice = blockIdx.x, h = blockIdx.y, b = blockIdx.z;
    int t = threadIdx.x;
    for (int i = t; i < 576; i += 128)
        sA[i] = attn[((long)(b * 8 + h)) * 576 + i];
    __syncthreads();
    int n = slice * 512 + t * 4;
    const float* vbase = qkv2 + ((long)(b * C2) + CC + h * 24) * PP;
    float4 acc[24];
#pragma unroll
    for (int c = 0; c < 24; ++c) acc[c] = make_float4(0.f, 0.f, 0.f, 0.f);
#pragma unroll 4
    for (int d = 0; d < 24; ++d) {
        float4 vv = *(const float4*)(vbase + (long)d * PP + n);
#pragma unroll
        for (int c = 0; c < 24; ++c) {
            float a = sA[c * 24 + d];
            acc[c].x += a * vv.x; acc[c].y += a * vv.y;
            acc[c].z += a * vv.z; acc[c].w += a * vv.w;
        }
    }
#pragma unroll
    for (int c = 0; c < 24; ++c)
        *(float4*)(out + ((long)(b * CC + h * 24 + c)) * PP + n) = acc[c];
}

// =========================================================================================
extern "C" void kernel_launch(void* const* d_in, const int* in_sizes, int n_in,
                              void* d_out, int out_size, void* d_ws, size_t ws_size,
                              hipStream_t stream)
{
    const float* x          = (const float*)d_in[0];
    const float* y          = (const float*)d_in[1];
    const float* temp       = (const float*)d_in[2];
    const float* qkv_w      = (const float*)d_in[3];
    const float* qkv_conv_w = (const float*)d_in[4];
    const float* proj_w     = (const float*)d_in[5];
    const float* k2_w       = (const float*)d_in[6];
    const float* k3_w       = (const float*)d_in[7];
    const float* k4_w       = (const float*)d_in[8];
    const float* deform_w   = (const float*)d_in[9];
    const float* deform_b   = (const float*)d_in[10];
    const float* pw_w       = (const float*)d_in[11];
    const float* pw_b       = (const float*)d_in[12];

    float* ws = (float*)d_ws;
    const long SZ_FULL = (long)BB * C2 * PP;     // 14,155,776
    const long SZ_HALF = (long)BB * CC * PP;     //  7,077,888

    float* bufA   = ws;
    float* qkv2   = ws + SZ_FULL;
    float* k2out  = ws + 2 * SZ_FULL;
    float* ovl    = k2out + (long)BB * C2 * 2116;
    ushort_t* poolb = (ushort_t*)ovl;
    ushort_t* catb  = (ushort_t*)ovl;
    ushort_t* wbuf = (ushort_t*)(ovl + SZ_HALF);
    ushort_t* wb4  = (ushort_t*)(ovl + SZ_HALF + 663552);
    float* offs   = ovl + SZ_HALF + 663552 + 55296;
    float* norms  = offs + (long)BB * 18 * PP;
    float* attnm  = norms + 2 * BB * CC;

    float* qkv1    = bufA;
    ushort_t* wb2  = (ushort_t*)bufA;
    ushort_t* scb  = (ushort_t*)bufA;
    float* kbuf    = bufA;
    float* feat    = bufA + SZ_HALF;
    float* attnout = bufA + SZ_HALF;
    float* attnp   = bufA + SZ_HALF;   // partials in dead feat space (consumed before attnout write)

    // 1. qkv = conv1x1(x, qkv_w)
    conv1x1_kernel<CC, false, false><<<dim3(9, 24, BB), 256, 0, stream>>>(
        x, qkv_w, nullptr, qkv1, (long)CC * PP, (long)C2 * PP);
    // 2. qkv = grouped 3x3 (groups=192), 4 px/thread
    dwconv_kernel<<<dim3(9, C2, BB), 256, 0, stream>>>(qkv1, qkv_conv_w, qkv2);
    // 3. poolb = bf16 px-major avgpool2(cat[q,y])   (qkv1 now dead)
    avgpool_bf16_kernel<<<dim3(36, BB), 256, 0, stream>>>(qkv2, y, poolb);
    // 4. wb2 = packed k2 weight fragments (into dead qkv1 space)
    prep_wpk_kernel<12><<<dim3(9 * 12 * 24 * 64 * 8 / 256), 256, 0, stream>>>(k2_w, wb2, 384);
    // 5. k2out = conv3x3 valid (48->46)  -- MFMA, double-buffered, b128 LDS
    conv48_mfma_kernel<<<dim3(12, 3, BB), 256, 0, stream>>>(poolb, wb2, k2out);
    // 6. packed weight preps: k3 and k4
    prep_wpk_kernel<12><<<dim3(9 * 12 * 24 * 64 * 8 / 256), 256, 0, stream>>>(k3_w, wbuf, 384);
    prep_wpk_kernel<1><<<dim3(9 * 1 * 24 * 64 * 8 / 256), 256, 0, stream>>>(k4_w, wb4, 18);
    // 7. catb = bf16 transposed cat (overlays dead poolb; live through disp 10)
    cvt_cat_kernel<<<dim3(144, BB), 256, 0, stream>>>(qkv2, y, catb);
    // 8. scb = bf16 px-major gated conv  -- MFMA v4: wloads-first + XCD swizzle + b128 LDS
    conv96_mfma_kernel<<<dim3(96, 3, BB), 256, 0, stream>>>(
        catb, wbuf, qkv2, y, k2out, scb);
    // 9. offset = conv3x3(scb, k4)  -- MFMA, double-buffered, b128 LDS
    k4_mfma_kernel<<<dim3(48, BB), 384, 0, stream>>>(scb, wb4, offs);
    // 10. feat = deform_conv v3 (8x16 tiles, 2304 blocks, 128 threads)
    deform_kernel<<<dim3(72, 8, BB), 128, 0, stream>>>(catb, offs, deform_w, deform_b, feat);
    // 11. k = conv1x1(relu(feat), pw_w) + pw_b
    conv1x1_kernel<CC, true, true><<<dim3(9, 12, BB), 256, 0, stream>>>(
        feat, pw_w, pw_b, kbuf, (long)CC * PP, (long)CC * PP);
    // 12. norms
    norm_kernel<<<dim3(CC, BB, 2), 256, 0, stream>>>(qkv2, kbuf, norms);
    // 13a. attn partial dots (q,k read once)
    attn_part_kernel<<<dim3(18, 8, BB), 192, 0, stream>>>(qkv2, kbuf, attnp);
    // 13b. reduce + normalize + softmax
    attn_reduce_kernel<<<dim3(8, BB), 256, 0, stream>>>(attnp, norms, temp, attnm);
    // 14. attnout = attn @ v (v read once)
    attn_apply_kernel<<<dim3(18, 8, BB), 128, 0, stream>>>(attnm, qkv2, attnout);
    // 15. out = conv1x1(attnout, proj_w)
    conv1x1_kernel<CC, false, false><<<dim3(9, 12, BB), 256, 0, stream>>>(
        attnout, proj_w, nullptr, (float*)d_out, (long)CC * PP, (long)CC * PP);
}

// Round 9
// 906.138 us; speedup vs baseline: 1.0139x; 1.0139x over previous
//
#include <hip/hip_runtime.h>
#include <math.h>

// Problem constants
#define BB 4
#define CC 192
#define HH 96
#define WW 96
#define PP (HH*WW)          // 9216
#define C2 (2*CC)           // 384

typedef unsigned short ushort_t;
typedef __bf16 bf16_t;
typedef bf16_t bf16x8 __attribute__((ext_vector_type(8)));
typedef float floatx16 __attribute__((ext_vector_type(16)));

__device__ __forceinline__ float sigmoidf_(float x) { return 1.f / (1.f + expf(-x)); }

__device__ __forceinline__ ushort_t f2bf(float f) {
    unsigned u = __builtin_bit_cast(unsigned, f);
    unsigned r = (u + 0x7fffu + ((u >> 16) & 1u)) >> 16;
    return (ushort_t)r;
}
__device__ __forceinline__ float bflo(unsigned u) {
    return __builtin_bit_cast(float, u << 16);
}
__device__ __forceinline__ float bfhi(unsigned u) {
    return __builtin_bit_cast(float, u & 0xffff0000u);
}

// ---------------- conv 1x1 ----------------------------------------------------------------
// unroll 8: 8 stride-PP float4 loads in flight (R7: neutral vs 4, kept).
template<int CIN, bool RELU, bool HASB>
__global__ __launch_bounds__(256) void conv1x1_kernel(
    const float* __restrict__ in, const float* __restrict__ w,
    const float* __restrict__ bias, float* __restrict__ out,
    long in_bs, long out_bs)
{
    int b = blockIdx.z;
    int co0 = blockIdx.y * 16;
    int p = blockIdx.x * 1024 + threadIdx.x * 4;
    const float* ip = in + (long)b * in_bs + p;
    float4 acc[16];
#pragma unroll
    for (int j = 0; j < 16; ++j) acc[j] = make_float4(0.f, 0.f, 0.f, 0.f);
#pragma unroll 8
    for (int ci = 0; ci < CIN; ++ci) {
        float4 xv = *(const float4*)(ip + (long)ci * PP);
        if (RELU) {
            xv.x = fmaxf(xv.x, 0.f); xv.y = fmaxf(xv.y, 0.f);
            xv.z = fmaxf(xv.z, 0.f); xv.w = fmaxf(xv.w, 0.f);
        }
#pragma unroll
        for (int j = 0; j < 16; ++j) {
            float wv = w[(long)(co0 + j) * CIN + ci];
            acc[j].x += wv * xv.x; acc[j].y += wv * xv.y;
            acc[j].z += wv * xv.z; acc[j].w += wv * xv.w;
        }
    }
#pragma unroll
    for (int j = 0; j < 16; ++j) {
        if (HASB) {
            float bb = bias[co0 + j];
            acc[j].x += bb; acc[j].y += bb; acc[j].z += bb; acc[j].w += bb;
        }
        *(float4*)(out + (long)b * out_bs + (long)(co0 + j) * PP + p) = acc[j];
    }
}

// ---------------- grouped conv 3x3, groups=192, 2in->2out, pad 1, 4px/thread -------------
__global__ __launch_bounds__(256) void dwconv_kernel(
    const float* __restrict__ in, const float* __restrict__ w, float* __restrict__ out)
{
    int b = blockIdx.z, co = blockIdx.y;
    int p = (blockIdx.x * 256 + threadIdx.x) * 4;
    int oy = p / WW, ox = p - oy * WW;
    int g = co >> 1;
    const float* w18 = w + (long)co * 18;
    float a0 = 0.f, a1 = 0.f, a2 = 0.f, a3 = 0.f;
#pragma unroll
    for (int i = 0; i < 2; ++i) {
        const float* ipl = in + ((long)(b * C2 + 2 * g + i)) * PP;
#pragma unroll
        for (int ky = 0; ky < 3; ++ky) {
            int yy = oy - 1 + ky;
            if ((unsigned)yy < (unsigned)HH) {
                const float* row = ipl + yy * WW;
                float v[6];
#pragma unroll
                for (int j = 0; j < 6; ++j) {
                    int xx = ox - 1 + j;
                    v[j] = ((unsigned)xx < (unsigned)WW) ? row[xx] : 0.f;
                }
#pragma unroll
                for (int kx = 0; kx < 3; ++kx) {
                    float wv = w18[i * 9 + ky * 3 + kx];
                    a0 += wv * v[kx]; a1 += wv * v[kx + 1];
                    a2 += wv * v[kx + 2]; a3 += wv * v[kx + 3];
                }
            }
        }
    }
    float4 r = make_float4(a0, a1, a2, a3);
    *(float4*)(out + ((long)(b * C2 + co)) * PP + p) = r;
}

// ---------------- fused avgpool 2x2 + bf16 + transpose: poolb[b][px48][ci] ---------------
__global__ __launch_bounds__(256) void avgpool_bf16_kernel(
    const float* __restrict__ qkv2, const float* __restrict__ y, ushort_t* __restrict__ poolb)
{
    __shared__ __align__(16) ushort_t sT[64 * 392];
    int b = blockIdx.y;
    int px0 = blockIdx.x * 64;
    int t = threadIdx.x;
    for (int idx = t; idx < 384 * 64; idx += 256) {
        int ci = idx >> 6, px = idx & 63;
        int p = px0 + px;
        int oy = p / 48, ox = p - oy * 48;
        const float* base = (ci < CC) ? qkv2 + ((long)(b * C2 + ci)) * PP
                                      : y + ((long)(b * CC + ci - CC)) * PP;
        const float* ipl = base + (oy * 2) * WW + ox * 2;
        float v = 0.25f * (ipl[0] + ipl[1] + ipl[WW] + ipl[WW + 1]);
        sT[px * 392 + ci] = f2bf(v);
    }
    __syncthreads();
    int px = t >> 2, qr = t & 3;
    ushort_t* dst = poolb + ((long)b * 2304 + px0 + px) * C2 + qr * 96;
    const ushort_t* srcl = sT + px * 392 + qr * 96;
#pragma unroll
    for (int k = 0; k < 96; k += 8)
        *(uint4*)(dst + k) = *(const uint4*)(srcl + k);
}

// ---------------- packed weight prep: wpk[((tap*NG+cg)*24+chunk)*64 + n*2+q][8] -----------
template<int NG>
__global__ __launch_bounds__(256) void prep_wpk_kernel(
    const float* __restrict__ w, ushort_t* __restrict__ wpk, int coutv)
{
    int i = blockIdx.x * 256 + threadIdx.x;
    int j = i & 7;
    int q = (i >> 3) & 1;
    int n = (i >> 4) & 31;
    int r = i >> 9;
    int chunk = r % 24;
    int r2 = r / 24;
    int cg = r2 % NG;
    int tap = r2 / NG;
    int co = cg * 32 + n;
    int ci = chunk * 16 + q * 8 + j;
    wpk[i] = (co < coutv) ? f2bf(w[((long)co * 384 + ci) * 9 + tap]) : (ushort_t)0;
}

// ---------------- conv48 MFMA: valid 3x3 48->46, double-buffered input staging -----------
// cell stride 24 ushorts (48 B): b128 LDS reads/writes, bank-tiling {0,12,24,...} -> 0 conflicts
__global__ __launch_bounds__(256) void conv48_mfma_kernel(
    const ushort_t* __restrict__ poolb, const ushort_t* __restrict__ wpk,
    float* __restrict__ out)
{
    __shared__ __align__(16) ushort_t sB[2][288 * 24];
    int b = blockIdx.z;
    int co0 = blockIdx.y * 128;
    int cgb = blockIdx.y * 4;
    int y0 = blockIdx.x * 4;
    int t = threadIdx.x;
    int w = t >> 6, lane = t & 63;
    int n = lane & 31, q = lane >> 5;
    int wc = w & 1, wn = w >> 1;
    const uint4* wq = (const uint4*)wpk;

    int pidx[3], rr[3], ccx[3];
#pragma unroll
    for (int xg = 0; xg < 3; ++xg) {
        int p = (wn * 3 + xg) * 32 + n;
        int pc = min(p, 183);
        pidx[xg] = p;
        rr[xg] = pc / 46;
        ccx[xg] = pc - rr[xg] * 46;
    }

    floatx16 acc[2][3];
#pragma unroll
    for (int a = 0; a < 2; ++a)
#pragma unroll
        for (int xg = 0; xg < 3; ++xg) acc[a][xg] = (floatx16)(0.f);

    const ushort_t* poolb_b = poolb + (long)b * 2304 * C2;

    bool sok[2]; long gof[2]; int lof[2]; bool sval[2];
#pragma unroll
    for (int s = 0; s < 2; ++s) {
        int c = t + s * 256;
        sval[s] = (c < 288);
        int cc = min(c, 287);
        int r = cc / 48, col = cc - r * 48;
        int iy = y0 + r;
        sok[s] = (iy < 48);
        gof[s] = ((long)(min(iy, 47) * 48 + col)) * C2;
        lof[s] = cc * 24;
    }
    uint4 sv[2][2];

#define C48_ISSUE(mm)                                                        \
    {                                                                        \
        int ci0 = (mm) * 16;                                                 \
        _Pragma("unroll")                                                    \
        for (int s = 0; s < 2; ++s) {                                        \
            if (sval[s] && sok[s]) {                                         \
                const ushort_t* sp = poolb_b + gof[s] + ci0;                 \
                sv[s][0] = *(const uint4*)(sp);                              \
                sv[s][1] = *(const uint4*)(sp + 8);                          \
            } else {                                                         \
                sv[s][0] = make_uint4(0u,0u,0u,0u);                          \
                sv[s][1] = make_uint4(0u,0u,0u,0u);                          \
            }                                                                \
        }                                                                    \
    }
#define C48_COMMIT(buf)                                                      \
    {                                                                        \
        _Pragma("unroll")                                                    \
        for (int s = 0; s < 2; ++s) {                                        \
            if (sval[s]) {                                                   \
                ushort_t* d = sB[buf] + lof[s];                              \
                *(uint4*)(d + 0) = sv[s][0];                                 \
                *(uint4*)(d + 8) = sv[s][1];                                 \
            }                                                                \
        }                                                                    \
    }

    C48_ISSUE(0); C48_COMMIT(0);
    __syncthreads();

    for (int m = 0; m < 24; ++m) {
        int cur = m & 1;
        if (m < 23) C48_ISSUE(m + 1);
#pragma unroll
        for (int ky = 0; ky < 3; ++ky) {
            uint4 wv[6];
#pragma unroll
            for (int kx = 0; kx < 3; ++kx)
#pragma unroll
                for (int a = 0; a < 2; ++a)
                    wv[kx * 2 + a] = wq[(long)(((ky * 3 + kx) * 12 + cgb + wc * 2 + a) * 24 + m) * 64 + lane];
#pragma unroll
            for (int kx = 0; kx < 3; ++kx) {
                bf16x8 af[2], bfm[3];
#pragma unroll
                for (int a = 0; a < 2; ++a)
                    af[a] = __builtin_bit_cast(bf16x8, wv[kx * 2 + a]);
#pragma unroll
                for (int xg = 0; xg < 3; ++xg) {
                    int cell = (rr[xg] + ky) * 48 + ccx[xg] + kx;
                    uint4 bv = *(const uint4*)(sB[cur] + cell * 24 + q * 8);
                    bfm[xg] = __builtin_bit_cast(bf16x8, bv);
                }
#pragma unroll
                for (int a = 0; a < 2; ++a)
#pragma unroll
                    for (int xg = 0; xg < 3; ++xg)
                        acc[a][xg] = __builtin_amdgcn_mfma_f32_32x32x16_bf16(
                            af[a], bfm[xg], acc[a][xg], 0, 0, 0);
            }
        }
        if (m < 23) C48_COMMIT(cur ^ 1);
        __syncthreads();
    }

#pragma unroll
    for (int a = 0; a < 2; ++a) {
        int cobase = co0 + (wc * 2 + a) * 32;
#pragma unroll
        for (int xg = 0; xg < 3; ++xg) {
            int oy = y0 + rr[xg], ox = ccx[xg];
            if (pidx[xg] >= 184 || oy >= 46) continue;
#pragma unroll
            for (int r = 0; r < 16; ++r) {
                int row = (r & 3) + 8 * (r >> 2) + 4 * q;
                out[((long)(b * C2 + cobase + row)) * 2116 + oy * 46 + ox] = acc[a][xg][r];
            }
        }
    }
}

// ---------------- cvt_cat: catb[b][px][ci] bf16 from cat(q=qkv2[0:192], y) ----------------
__global__ __launch_bounds__(256) void cvt_cat_kernel(
    const float* __restrict__ qkv2, const float* __restrict__ y, ushort_t* __restrict__ catb)
{
    __shared__ __align__(16) ushort_t sT[64 * 392];
    int b = blockIdx.y;
    int px0 = blockIdx.x * 64;
    int t = threadIdx.x;
    for (int idx = t; idx < 384 * 64; idx += 256) {
        int ci = idx >> 6, px = idx & 63;
        const float* src = (ci < CC) ? qkv2 + ((long)(b * C2 + ci)) * PP
                                     : y + ((long)(b * CC + ci - CC)) * PP;
        sT[px * 392 + ci] = f2bf(src[px0 + px]);
    }
    __syncthreads();
    int px = t >> 2, qr = t & 3;
    ushort_t* dst = catb + ((long)b * PP + px0 + px) * C2 + qr * 96;
    const ushort_t* srcl = sT + px * 392 + qr * 96;
#pragma unroll
    for (int k = 0; k < 96; k += 8)
        *(uint4*)(dst + k) = *(const uint4*)(srcl + k);
}

// ---------------- conv96 MFMA: 1 row/block, 1152 blocks, wave = 32co x 96px --------------
// grid (96, 3, B); block 256 (4 waves). LDS: 3 rows x 98 cols, double-buffered.
// v4 = v3 (weight-loads-first + XCD stripe swizzle) + b128 LDS (cell stride 24 ushorts).
__global__ __launch_bounds__(256) void conv96_mfma_kernel(
    const ushort_t* __restrict__ catb, const ushort_t* __restrict__ wpk,
    const float* __restrict__ qkv2, const float* __restrict__ yy,
    const float* __restrict__ k2out, ushort_t* __restrict__ scb)
{
    __shared__ __align__(16) ushort_t sB[2][294 * 24];
    int b = blockIdx.z;
    int co0 = blockIdx.y * 128;
    int cgb = blockIdx.y * 4;
    int bx = blockIdx.x;
    int yl = (bx & 7) * 12 + (bx >> 3);   // XCD stripe swizzle (bijective on [0,96))
    int t = threadIdx.x;
    int w = t >> 6, lane = t & 63;
    int n = lane & 31, q = lane >> 5;
    const uint4* wq = (const uint4*)wpk;

    floatx16 acc[3];
#pragma unroll
    for (int xg = 0; xg < 3; ++xg) acc[xg] = (floatx16)(0.f);

    const ushort_t* catb_b = catb + (long)b * PP * C2;

    // staging geometry: 294 cells = 3 rows (yl-1..yl+1) x 98 cols (x=-1..96)
    bool sok[2]; long gof[2]; int lof[2]; bool sval[2];
#pragma unroll
    for (int s = 0; s < 2; ++s) {
        int c = t + s * 256;
        sval[s] = (c < 294);
        int cc = min(c, 293);
        int r = cc / 98, col = cc - r * 98;
        int iy = yl - 1 + r, ix = col - 1;
        sok[s] = (iy >= 0 && iy < HH && ix >= 0 && ix < WW);
        gof[s] = ((long)(min(max(iy, 0), HH - 1) * WW + min(max(ix, 0), WW - 1))) * C2;
        lof[s] = cc * 24;
    }
    uint4 sv[2][2];

#define C96_ISSUE(mm)                                                        \
    {                                                                        \
        int ci0 = (mm) * 16;                                                 \
        _Pragma("unroll")                                                    \
        for (int s = 0; s < 2; ++s) {                                        \
            if (sval[s] && sok[s]) {                                         \
                const ushort_t* sp = catb_b + gof[s] + ci0;                  \
                sv[s][0] = *(const uint4*)(sp);                              \
                sv[s][1] = *(const uint4*)(sp + 8);                          \
            } else {                                                         \
                sv[s][0] = make_uint4(0u,0u,0u,0u);                          \
                sv[s][1] = make_uint4(0u,0u,0u,0u);                          \
            }                                                                \
        }                                                                    \
    }
#define C96_COMMIT(buf)                                                      \
    {                                                                        \
        _Pragma("unroll")                                                    \
        for (int s = 0; s < 2; ++s) {                                        \
            if (sval[s]) {                                                   \
                ushort_t* d = sB[buf] + lof[s];                              \
                *(uint4*)(d + 0) = sv[s][0];                                 \
                *(uint4*)(d + 8) = sv[s][1];                                 \
            }                                                                \
        }                                                                    \
    }

    C96_ISSUE(0); C96_COMMIT(0);
    __syncthreads();

    for (int m = 0; m < 24; ++m) {
        int cur = m & 1;
        // weight fragments FIRST (before staging issue): the MFMA's weight-wait
        // then leaves the staging loads in flight (vmcnt FIFO order).
        uint4 wv[9];
#pragma unroll
        for (int tap = 0; tap < 9; ++tap)
            wv[tap] = wq[(long)((tap * 12 + cgb + w) * 24 + m) * 64 + lane];
        if (m < 23) C96_ISSUE(m + 1);
#pragma unroll
        for (int ky = 0; ky < 3; ++ky) {
#pragma unroll
            for (int kx = 0; kx < 3; ++kx) {
                bf16x8 af = __builtin_bit_cast(bf16x8, wv[ky * 3 + kx]);
#pragma unroll
                for (int xg = 0; xg < 3; ++xg) {
                    int cell = ky * 98 + xg * 32 + n + kx;
                    uint4 bv = *(const uint4*)(sB[cur] + cell * 24 + q * 8);
                    bf16x8 bfm = __builtin_bit_cast(bf16x8, bv);
                    acc[xg] = __builtin_amdgcn_mfma_f32_32x32x16_bf16(af, bfm, acc[xg], 0, 0, 0);
                }
            }
        }
        if (m < 23) C96_COMMIT(cur ^ 1);
        __syncthreads();
    }

    // epilogue: scb[b][px][co] = bf16( acc * sigmoid(cat + nearest(k2out)) )
    int iy46 = (yl * 46) / 96;
    int cobase = co0 + w * 32;
#pragma unroll
    for (int xg = 0; xg < 3; ++xg) {
        int x = xg * 32 + n;
        int ix46 = (x * 46) / 96;
        ushort_t* dst = scb + ((long)(b * PP + yl * WW + x)) * C2;
#pragma unroll
        for (int g = 0; g < 4; ++g) {
            int cog = cobase + 8 * g + 4 * q;
            ushort_t pk[4];
#pragma unroll
            for (int j = 0; j < 4; ++j) {
                int co = cog + j;
                const float* gsrc = (co < CC) ? qkv2 + ((long)(b * C2 + co)) * PP
                                              : yy + ((long)(b * CC + co - CC)) * PP;
                float kv = k2out[((long)(b * C2 + co)) * 2116 + iy46 * 46 + ix46];
                float gg = gsrc[yl * WW + x] + kv;
                pk[j] = f2bf(acc[xg][4 * g + j] * sigmoidf_(gg));
            }
            *(uint2*)(dst + cog) = *(uint2*)pk;
        }
    }
}

// ---------------- k4 MFMA: offs = conv3x3(scb), M=32 pad, double-buffered ----------------
__global__ __launch_bounds__(384) void k4_mfma_kernel(
    const ushort_t* __restrict__ scb, const ushort_t* __restrict__ wpk4,
    float* __restrict__ out)
{
    __shared__ __align__(16) ushort_t sB[2][392 * 24];
    int b = blockIdx.y;
    int y0 = blockIdx.x * 2;
    int t = threadIdx.x;
    int w = t / 64, lane = t & 63;
    int n = lane & 31, q = lane >> 5;
    int wr = w / 3, xg = w - wr * 3;
    const uint4* wq = (const uint4*)wpk4;

    floatx16 acc = (floatx16)(0.f);
    const ushort_t* scb_b = scb + (long)b * PP * C2;

    bool sok[2]; long gof[2]; int lof[2]; bool sval[2];
#pragma unroll
    for (int s = 0; s < 2; ++s) {
        int c = t + s * 384;
        sval[s] = (c < 392);
        int cc = min(c, 391);
        int r = cc / 98, col = cc - r * 98;
        int iy = y0 - 1 + r, ix = col - 1;
        sok[s] = (iy >= 0 && iy < HH && ix >= 0 && ix < WW);
        gof[s] = ((long)(min(max(iy, 0), HH - 1) * WW + min(max(ix, 0), WW - 1))) * C2;
        lof[s] = cc * 24;
    }
    uint4 sv[2][2];

#define K4_ISSUE(mm)                                                         \
    {                                                                        \
        int ci0 = (mm) * 16;                                                 \
        _Pragma("unroll")                                                    \
        for (int s = 0; s < 2; ++s) {                                        \
            if (sval[s] && sok[s]) {                                         \
                const ushort_t* sp = scb_b + gof[s] + ci0;                   \
                sv[s][0] = *(const uint4*)(sp);                              \
                sv[s][1] = *(const uint4*)(sp + 8);                          \
            } else {                                                         \
                sv[s][0] = make_uint4(0u,0u,0u,0u);                          \
                sv[s][1] = make_uint4(0u,0u,0u,0u);                          \
            }                                                                \
        }                                                                    \
    }
#define K4_COMMIT(buf)                                                       \
    {                                                                        \
        _Pragma("unroll")                                                    \
        for (int s = 0; s < 2; ++s) {                                        \
            if (sval[s]) {                                                   \
                ushort_t* d = sB[buf] + lof[s];                              \
                *(uint4*)(d + 0) = sv[s][0];                                 \
                *(uint4*)(d + 8) = sv[s][1];                                 \
            }                                                                \
        }                                                                    \
    }

    K4_ISSUE(0); K4_COMMIT(0);
    __syncthreads();

    for (int m = 0; m < 24; ++m) {
        int cur = m & 1;
        if (m < 23) K4_ISSUE(m + 1);
#pragma unroll
        for (int ky = 0; ky < 3; ++ky) {
            uint4 wv[3];
#pragma unroll
            for (int kx = 0; kx < 3; ++kx)
                wv[kx] = wq[(long)(((ky * 3 + kx) * 24) + m) * 64 + lane];
#pragma unroll
            for (int kx = 0; kx < 3; ++kx) {
                bf16x8 af = __builtin_bit_cast(bf16x8, wv[kx]);
                int col = xg * 32 + n + kx;
                uint4 bv = *(const uint4*)(sB[cur] + ((wr + ky) * 98 + col) * 24 + q * 8);
                bf16x8 bf = __builtin_bit_cast(bf16x8, bv);
                acc = __builtin_amdgcn_mfma_f32_32x32x16_bf16(af, bf, acc, 0, 0, 0);
            }
        }
        if (m < 23) K4_COMMIT(cur ^ 1);
        __syncthreads();
    }

    int yl = y0 + wr;
    int x = xg * 32 + n;
#pragma unroll
    for (int r = 0; r < 16; ++r) {
        int row = (r & 3) + 8 * (r >> 2) + 4 * q;
        if (row < 18)
            out[((long)(b * 18 + row)) * PP + yl * WW + x] = acc[r];
    }
}

// ---------------- deformable conv, bf16 LDS tile from catb -------------------------------
// EXACT r3 body+geometry (153 us plateau). Closed: schedule edits (R4, R5) and geometry
// edits (R8) all regressed; runtime does not respond to added waves or reordering.
#define DW 22
__global__ __launch_bounds__(256) void deform_kernel(
    const ushort_t* __restrict__ catb, const float* __restrict__ offs,
    const float* __restrict__ w, const float* __restrict__ bias, float* __restrict__ out)
{
    __shared__ __align__(16) ushort_t sQ[DW * DW * 24];
    int b = blockIdx.z, g = blockIdx.y;
    int tile = blockIdx.x;
    int ty0 = (tile / 6) * 16, tx0 = (tile % 6) * 16;
    int wy0 = ty0 - 3, wx0 = tx0 - 3;
    int t = threadIdx.x;
    int oy = ty0 + (t >> 4), ox = tx0 + (t & 15);
    int p = oy * WW + ox;

    const ushort_t* cb = catb + (long)b * PP * C2 + g * 24;
    for (int idx = t; idx < 484 * 3; idx += 256) {
        int cell = idx / 3, part = idx - cell * 3;
        int sy = cell / DW, sx = cell - sy * DW;
        int syc = min(max(wy0 + sy, 0), HH - 1);
        int sxc = min(max(wx0 + sx, 0), WW - 1);
        uint4 v = *(const uint4*)(cb + ((long)(syc * WW + sxc)) * C2 + part * 8);
        *(uint4*)(sQ + cell * 24 + part * 8) = v;
    }
    __syncthreads();

    const float* ob = offs + (long)b * 18 * PP;
    float acc[24];
#pragma unroll
    for (int o = 0; o < 24; ++o) acc[o] = 0.f;

    for (int k = 0; k < 9; ++k) {
        float dy = ob[(2 * k) * PP + p];
        float dx = ob[(2 * k + 1) * PP + p];
        float mk = sigmoidf_(ob[k * PP + p]);
        float py = dy + (float)(oy - 1 + k / 3);
        float px = dx + (float)(ox - 1 + (k % 3));
        float fy = floorf(py), fx = floorf(px);
        int y0 = (int)fy, x0 = (int)fx;
        float ly = py - fy, lx = px - fx;
        float w00 = (1.f - ly) * (1.f - lx), w01 = (1.f - ly) * lx;
        float w10 = ly * (1.f - lx), w11 = ly * lx;
        bool vy0 = (y0 >= 0 && y0 <= HH - 1), vy1 = (y0 + 1 <= HH - 1) && (y0 + 1 >= 0);
        bool vx0 = (x0 >= 0 && x0 <= WW - 1), vx1 = (x0 + 1 <= WW - 1) && (x0 + 1 >= 0);
        w00 = (vy0 && vx0) ? w00 * mk : 0.f;
        w01 = (vy0 && vx1) ? w01 * mk : 0.f;
        w10 = (vy1 && vx0) ? w10 * mk : 0.f;
        w11 = (vy1 && vx1) ? w11 * mk : 0.f;
        float vals[24];
        bool inwin = (y0 >= wy0) && (y0 - wy0 <= DW - 2) && (x0 >= wx0) && (x0 - wx0 <= DW - 2);
        if (inwin) {
            int c00 = (y0 - wy0) * DW + (x0 - wx0);
            const ushort_t* s00 = sQ + c00 * 24;
#pragma unroll
            for (int part = 0; part < 3; ++part) {
                uint4 A = *(const uint4*)(s00 + part * 8);
                uint4 Bv = *(const uint4*)(s00 + 24 + part * 8);
                uint4 Cv = *(const uint4*)(s00 + DW * 24 + part * 8);
                uint4 Dv = *(const uint4*)(s00 + DW * 24 + 24 + part * 8);
                const unsigned* au = (const unsigned*)&A;
                const unsigned* bu = (const unsigned*)&Bv;
                const unsigned* cu = (const unsigned*)&Cv;
                const unsigned* du = (const unsigned*)&Dv;
#pragma unroll
                for (int u = 0; u < 4; ++u) {
                    int ci = part * 8 + u * 2;
                    vals[ci]     = w00 * bflo(au[u]) + w01 * bflo(bu[u])
                                 + w10 * bflo(cu[u]) + w11 * bflo(du[u]);
                    vals[ci + 1] = w00 * bfhi(au[u]) + w01 * bfhi(bu[u])
                                 + w10 * bfhi(cu[u]) + w11 * bfhi(du[u]);
                }
            }
        } else {
            int y0c = min(max(y0, 0), HH - 1), y1c = min(max(y0 + 1, 0), HH - 1);
            int x0c = min(max(x0, 0), WW - 1), x1c = min(max(x0 + 1, 0), WW - 1);
            const ushort_t* p00 = cb + ((long)(y0c * WW + x0c)) * C2;
            const ushort_t* p01 = cb + ((long)(y0c * WW + x1c)) * C2;
            const ushort_t* p10 = cb + ((long)(y1c * WW + x0c)) * C2;
            const ushort_t* p11 = cb + ((long)(y1c * WW + x1c)) * C2;
#pragma unroll
            for (int part = 0; part < 3; ++part) {
                uint4 A = *(const uint4*)(p00 + part * 8);
                uint4 Bv = *(const uint4*)(p01 + part * 8);
                uint4 Cv = *(const uint4*)(p10 + part * 8);
                uint4 Dv = *(const uint4*)(p11 + part * 8);
                const unsigned* au = (const unsigned*)&A;
                const unsigned* bu = (const unsigned*)&Bv;
                const unsigned* cu = (const unsigned*)&Cv;
                const unsigned* du = (const unsigned*)&Dv;
#pragma unroll
                for (int u = 0; u < 4; ++u) {
                    int ci = part * 8 + u * 2;
                    vals[ci]     = w00 * bflo(au[u]) + w01 * bflo(bu[u])
                                 + w10 * bflo(cu[u]) + w11 * bflo(du[u]);
                    vals[ci + 1] = w00 * bfhi(au[u]) + w01 * bfhi(bu[u])
                                 + w10 * bfhi(cu[u]) + w11 * bfhi(du[u]);
                }
            }
        }
        const float* wg = w + (long)g * 24 * 216 + k;
#pragma unroll
        for (int o = 0; o < 24; ++o) {
            const float* wr = wg + (long)o * 216;
            float s = acc[o];
#pragma unroll
            for (int ci = 0; ci < 24; ++ci) s += wr[ci * 9] * vals[ci];
            acc[o] = s;
        }
    }
#pragma unroll
    for (int o = 0; o < 24; ++o)
        out[((long)(b * CC + g * 24 + o)) * PP + p] = acc[o] + bias[g * 24 + o];
}

// ---------------- attention stage A: partial 24x24 dot blocks + fused norm partials ------
// grid (18, 8, B), block 192 (3 waves). Each wave owns 3 of nine 8x8 (c,d) tiles.
// q,k each read ONCE from global. NEW: while each chunk is in LDS, threads (4 per row x
// 48 rows, uniform, no divergence) accumulate per-row sum-of-squares -> normp partials.
// This eliminates norm_kernel's entire 56 MB re-read of q,k.
__global__ __launch_bounds__(192) void attn_part_kernel(
    const float* __restrict__ q, const float* __restrict__ kb,
    float* __restrict__ part, float* __restrict__ normp)
{
    __shared__ __align__(16) float sQ[24 * 260];   // 260-pad: row starts at bank 4*r -> 0 conflicts
    __shared__ __align__(16) float sK[24 * 260];
    __shared__ float sS[192];
    int slice = blockIdx.x, h = blockIdx.y, b = blockIdx.z;
    int t = threadIdx.x;
    int w = t >> 6, lane = t & 63;
    int a_ = lane >> 3, b_ = lane & 7;
    const float* qbase = q + ((long)(b * C2) + h * 24) * PP;
    const float* kbase = kb + ((long)(b * CC) + h * 24) * PP;

    // sumsq assignment: row rr = t/4 (0..23 = q rows, 24..47 = k rows), quarter qq = t%4
    int rr = t >> 2, qq = t & 3;
    const float* srow = (rr < 24) ? (sQ + rr * 260) : (sK + (rr - 24) * 260);
    srow += qq * 64;
    float ssq = 0.f;

    float4 acc[3];
#pragma unroll
    for (int i = 0; i < 3; ++i) acc[i] = make_float4(0.f, 0.f, 0.f, 0.f);

    for (int sc = 0; sc < 2; ++sc) {
        int n0 = slice * 512 + sc * 256;
        for (int i = t; i < 1536; i += 192) {
            int r = i >> 6, c4 = i & 63;
            *(float4*)(sQ + r * 260 + c4 * 4) =
                *(const float4*)(qbase + (long)r * PP + n0 + c4 * 4);
            *(float4*)(sK + r * 260 + c4 * 4) =
                *(const float4*)(kbase + (long)r * PP + n0 + c4 * 4);
        }
        __syncthreads();
        // norm partial: 16 float4 from this thread's row-quarter
#pragma unroll 4
        for (int p4 = 0; p4 < 16; ++p4) {
            float4 v = *(const float4*)(srow + p4 * 4);
            ssq += v.x * v.x + v.y * v.y + v.z * v.z + v.w * v.w;
        }
#pragma unroll
        for (int t3 = 0; t3 < 3; ++t3) {
            int tile = w * 3 + t3;
            const float* qr = sQ + ((tile / 3) * 8 + a_) * 260;
            const float* kr = sK + ((tile % 3) * 8 + b_) * 260;
            float4 s = acc[t3];
#pragma unroll 8
            for (int p4 = 0; p4 < 64; ++p4) {
                float4 qv = *(const float4*)(qr + p4 * 4);
                float4 kv = *(const float4*)(kr + p4 * 4);
                s.x += qv.x * kv.x; s.y += qv.y * kv.y;
                s.z += qv.z * kv.z; s.w += qv.w * kv.w;
            }
            acc[t3] = s;
        }
        __syncthreads();
    }
    // reduce 4 quarters per row and emit norm partials
    sS[t] = ssq;
    __syncthreads();
    if (t < 48) {
        float tot = sS[4 * t] + sS[4 * t + 1] + sS[4 * t + 2] + sS[4 * t + 3];
        normp[(((long)(b * 8 + h) * 18) + slice) * 48 + t] = tot;
    }
#pragma unroll
    for (int t3 = 0; t3 < 3; ++t3) {
        int tile = w * 3 + t3;
        int c = (tile / 3) * 8 + a_;
        int d = (tile % 3) * 8 + b_;
        float s = acc[t3].x + acc[t3].y + acc[t3].z + acc[t3].w;
        part[(((long)(b * 8 + h) * 18) + slice) * 576 + c * 24 + d] = s;
    }
}

// ---------------- attention stage B: reduce slices + norms + normalize + softmax ---------
__global__ __launch_bounds__(256) void attn_reduce_kernel(
    const float* __restrict__ part, const float* __restrict__ normp,
    const float* __restrict__ temp, float* __restrict__ attn)
{
    __shared__ float L[576];
    __shared__ float nrm[48];
    __shared__ float rmx[24], rsm[24];
    int h = blockIdx.x, b = blockIdx.y;
    int t = threadIdx.x;
    const float* pb = part + ((long)(b * 8 + h) * 18) * 576;
    const float* npb = normp + ((long)(b * 8 + h) * 18) * 48;
    float tmp = temp[h];
    if (t < 48) {
        float s = 0.f;
#pragma unroll
        for (int sl = 0; sl < 18; ++sl) s += npb[sl * 48 + t];
        nrm[t] = fmaxf(sqrtf(s), 1e-12f);
    }
    __syncthreads();
    for (int pid = t; pid < 576; pid += 256) {
        float s = 0.f;
#pragma unroll
        for (int sl = 0; sl < 18; ++sl) s += pb[sl * 576 + pid];
        int c = pid / 24, d = pid - c * 24;
        L[pid] = s / (nrm[c] * nrm[24 + d]) * tmp;
    }
    __syncthreads();
    if (t < 24) {
        float mx = -3.4e38f;
#pragma unroll
        for (int j = 0; j < 24; ++j) mx = fmaxf(mx, L[t * 24 + j]);
        float sm = 0.f;
#pragma unroll
        for (int j = 0; j < 24; ++j) sm += expf(L[t * 24 + j] - mx);
        rmx[t] = mx; rsm[t] = 1.f / sm;
    }
    __syncthreads();
    for (int pid = t; pid < 576; pid += 256) {
        int c = pid / 24;
        attn[((long)(b * 8 + h)) * 576 + pid] = expf(L[pid] - rmx[c]) * rsm[c];
    }
}

// ---------------- attn @ v: block per (slice, h, b); v read ONCE ------------------------
__global__ __launch_bounds__(128) void attn_apply_kernel(
    const float* __restrict__ attn, const float* __restrict__ qkv2, float* __restrict__ out)
{
    __shared__ float sA[576];
    int slice = blockIdx.x, h = blockIdx.y, b = blockIdx.z;
    int t = threadIdx.x;
    for (int i = t; i < 576; i += 128)
        sA[i] = attn[((long)(b * 8 + h)) * 576 + i];
    __syncthreads();
    int n = slice * 512 + t * 4;
    const float* vbase = qkv2 + ((long)(b * C2) + CC + h * 24) * PP;
    float4 acc[24];
#pragma unroll
    for (int c = 0; c < 24; ++c) acc[c] = make_float4(0.f, 0.f, 0.f, 0.f);
#pragma unroll 4
    for (int d = 0; d < 24; ++d) {
        float4 vv = *(const float4*)(vbase + (long)d * PP + n);
#pragma unroll
        for (int c = 0; c < 24; ++c) {
            float a = sA[c * 24 + d];
            acc[c].x += a * vv.x; acc[c].y += a * vv.y;
            acc[c].z += a * vv.z; acc[c].w += a * vv.w;
        }
    }
#pragma unroll
    for (int c = 0; c < 24; ++c)
        *(float4*)(out + ((long)(b * CC + h * 24 + c)) * PP + n) = acc[c];
}

// =========================================================================================
extern "C" void kernel_launch(void* const* d_in, const int* in_sizes, int n_in,
                              void* d_out, int out_size, void* d_ws, size_t ws_size,
                              hipStream_t stream)
{
    const float* x          = (const float*)d_in[0];
    const float* y          = (const float*)d_in[1];
    const float* temp       = (const float*)d_in[2];
    const float* qkv_w      = (const float*)d_in[3];
    const float* qkv_conv_w = (const float*)d_in[4];
    const float* proj_w     = (const float*)d_in[5];
    const float* k2_w       = (const float*)d_in[6];
    const float* k3_w       = (const float*)d_in[7];
    const float* k4_w       = (const float*)d_in[8];
    const float* deform_w   = (const float*)d_in[9];
    const float* deform_b   = (const float*)d_in[10];
    const float* pw_w       = (const float*)d_in[11];
    const float* pw_b       = (const float*)d_in[12];

    float* ws = (float*)d_ws;
    const long SZ_FULL = (long)BB * C2 * PP;     // 14,155,776
    const long SZ_HALF = (long)BB * CC * PP;     //  7,077,888

    float* bufA   = ws;
    float* qkv2   = ws + SZ_FULL;
    float* k2out  = ws + 2 * SZ_FULL;
    float* ovl    = k2out + (long)BB * C2 * 2116;
    ushort_t* poolb = (ushort_t*)ovl;
    ushort_t* catb  = (ushort_t*)ovl;
    ushort_t* wbuf = (ushort_t*)(ovl + SZ_HALF);
    ushort_t* wb4  = (ushort_t*)(ovl + SZ_HALF + 663552);
    float* offs   = ovl + SZ_HALF + 663552 + 55296;
    float* attnm  = offs + (long)BB * 18 * PP;

    float* qkv1    = bufA;
    ushort_t* wb2  = (ushort_t*)bufA;
    ushort_t* scb  = (ushort_t*)bufA;
    float* kbuf    = bufA;
    float* feat    = bufA + SZ_HALF;
    float* attnout = bufA + SZ_HALF;
    float* attnp   = bufA + SZ_HALF;                    // partials in dead feat space
    float* normp   = attnp + (long)BB * 8 * 18 * 576;   // norm partials right after

    // 1. qkv = conv1x1(x, qkv_w)
    conv1x1_kernel<CC, false, false><<<dim3(9, 24, BB), 256, 0, stream>>>(
        x, qkv_w, nullptr, qkv1, (long)CC * PP, (long)C2 * PP);
    // 2. qkv = grouped 3x3 (groups=192), 4 px/thread
    dwconv_kernel<<<dim3(9, C2, BB), 256, 0, stream>>>(qkv1, qkv_conv_w, qkv2);
    // 3. poolb = bf16 px-major avgpool2(cat[q,y])   (qkv1 now dead)
    avgpool_bf16_kernel<<<dim3(36, BB), 256, 0, stream>>>(qkv2, y, poolb);
    // 4. wb2 = packed k2 weight fragments (into dead qkv1 space)
    prep_wpk_kernel<12><<<dim3(9 * 12 * 24 * 64 * 8 / 256), 256, 0, stream>>>(k2_w, wb2, 384);
    // 5. k2out = conv3x3 valid (48->46)  -- MFMA, double-buffered, b128 LDS
    conv48_mfma_kernel<<<dim3(12, 3, BB), 256, 0, stream>>>(poolb, wb2, k2out);
    // 6. packed weight preps: k3 and k4
    prep_wpk_kernel<12><<<dim3(9 * 12 * 24 * 64 * 8 / 256), 256, 0, stream>>>(k3_w, wbuf, 384);
    prep_wpk_kernel<1><<<dim3(9 * 1 * 24 * 64 * 8 / 256), 256, 0, stream>>>(k4_w, wb4, 18);
    // 7. catb = bf16 transposed cat (overlays dead poolb; live through disp 10)
    cvt_cat_kernel<<<dim3(144, BB), 256, 0, stream>>>(qkv2, y, catb);
    // 8. scb = bf16 px-major gated conv  -- MFMA v4: wloads-first + XCD swizzle + b128 LDS
    conv96_mfma_kernel<<<dim3(96, 3, BB), 256, 0, stream>>>(
        catb, wbuf, qkv2, y, k2out, scb);
    // 9. offset = conv3x3(scb, k4)  -- MFMA, double-buffered, b128 LDS
    k4_mfma_kernel<<<dim3(48, BB), 384, 0, stream>>>(scb, wb4, offs);
    // 10. feat = deform_conv (exact r3 body, closed)
    deform_kernel<<<dim3(36, 8, BB), 256, 0, stream>>>(catb, offs, deform_w, deform_b, feat);
    // 11. k = conv1x1(relu(feat), pw_w) + pw_b
    conv1x1_kernel<CC, true, true><<<dim3(9, 12, BB), 256, 0, stream>>>(
        feat, pw_w, pw_b, kbuf, (long)CC * PP, (long)CC * PP);
    // 12. attn partial dots + fused norm partials (q,k read once; norm_kernel eliminated)
    attn_part_kernel<<<dim3(18, 8, BB), 192, 0, stream>>>(qkv2, kbuf, attnp, normp);
    // 13. reduce + norms + normalize + softmax
    attn_reduce_kernel<<<dim3(8, BB), 256, 0, stream>>>(attnp, normp, temp, attnm);
    // 14. attnout = attn @ v (v read once)
    attn_apply_kernel<<<dim3(18, 8, BB), 128, 0, stream>>>(attnm, qkv2, attnout);
    // 15. out = conv1x1(attnout, proj_w)
    conv1x1_kernel<CC, false, false><<<dim3(9, 12, BB), 256, 0, stream>>>(
        attnout, proj_w, nullptr, (float*)d_out, (long)CC * PP, (long)CC * PP);
}

// Round 10
// 855.908 us; speedup vs baseline: 1.0734x; 1.0587x over previous
//
#include <hip/hip_runtime.h>
#include <math.h>

// Problem constants
#define BB 4
#define CC 192
#define HH 96
#define WW 96
#define PP (HH*WW)          // 9216
#define C2 (2*CC)           // 384

typedef unsigned short ushort_t;
typedef __bf16 bf16_t;
typedef bf16_t bf16x8 __attribute__((ext_vector_type(8)));
typedef float floatx16 __attribute__((ext_vector_type(16)));

__device__ __forceinline__ float sigmoidf_(float x) { return 1.f / (1.f + expf(-x)); }

__device__ __forceinline__ ushort_t f2bf(float f) {
    unsigned u = __builtin_bit_cast(unsigned, f);
    unsigned r = (u + 0x7fffu + ((u >> 16) & 1u)) >> 16;
    return (ushort_t)r;
}
__device__ __forceinline__ float bflo(unsigned u) {
    return __builtin_bit_cast(float, u << 16);
}
__device__ __forceinline__ float bfhi(unsigned u) {
    return __builtin_bit_cast(float, u & 0xffff0000u);
}

// ---------------- conv 1x1 ----------------------------------------------------------------
// unroll 8: 8 stride-PP float4 loads in flight (R7: neutral vs 4, kept).
template<int CIN, bool RELU, bool HASB>
__global__ __launch_bounds__(256) void conv1x1_kernel(
    const float* __restrict__ in, const float* __restrict__ w,
    const float* __restrict__ bias, float* __restrict__ out,
    long in_bs, long out_bs)
{
    int b = blockIdx.z;
    int co0 = blockIdx.y * 16;
    int p = blockIdx.x * 1024 + threadIdx.x * 4;
    const float* ip = in + (long)b * in_bs + p;
    float4 acc[16];
#pragma unroll
    for (int j = 0; j < 16; ++j) acc[j] = make_float4(0.f, 0.f, 0.f, 0.f);
#pragma unroll 8
    for (int ci = 0; ci < CIN; ++ci) {
        float4 xv = *(const float4*)(ip + (long)ci * PP);
        if (RELU) {
            xv.x = fmaxf(xv.x, 0.f); xv.y = fmaxf(xv.y, 0.f);
            xv.z = fmaxf(xv.z, 0.f); xv.w = fmaxf(xv.w, 0.f);
        }
#pragma unroll
        for (int j = 0; j < 16; ++j) {
            float wv = w[(long)(co0 + j) * CIN + ci];
            acc[j].x += wv * xv.x; acc[j].y += wv * xv.y;
            acc[j].z += wv * xv.z; acc[j].w += wv * xv.w;
        }
    }
#pragma unroll
    for (int j = 0; j < 16; ++j) {
        if (HASB) {
            float bb = bias[co0 + j];
            acc[j].x += bb; acc[j].y += bb; acc[j].z += bb; acc[j].w += bb;
        }
        *(float4*)(out + (long)b * out_bs + (long)(co0 + j) * PP + p) = acc[j];
    }
}

// ---------------- grouped conv 3x3, groups=192, 2in->2out, pad 1, 4px/thread -------------
__global__ __launch_bounds__(256) void dwconv_kernel(
    const float* __restrict__ in, const float* __restrict__ w, float* __restrict__ out)
{
    int b = blockIdx.z, co = blockIdx.y;
    int p = (blockIdx.x * 256 + threadIdx.x) * 4;
    int oy = p / WW, ox = p - oy * WW;
    int g = co >> 1;
    const float* w18 = w + (long)co * 18;
    float a0 = 0.f, a1 = 0.f, a2 = 0.f, a3 = 0.f;
#pragma unroll
    for (int i = 0; i < 2; ++i) {
        const float* ipl = in + ((long)(b * C2 + 2 * g + i)) * PP;
#pragma unroll
        for (int ky = 0; ky < 3; ++ky) {
            int yy = oy - 1 + ky;
            if ((unsigned)yy < (unsigned)HH) {
                const float* row = ipl + yy * WW;
                float v[6];
#pragma unroll
                for (int j = 0; j < 6; ++j) {
                    int xx = ox - 1 + j;
                    v[j] = ((unsigned)xx < (unsigned)WW) ? row[xx] : 0.f;
                }
#pragma unroll
                for (int kx = 0; kx < 3; ++kx) {
                    float wv = w18[i * 9 + ky * 3 + kx];
                    a0 += wv * v[kx]; a1 += wv * v[kx + 1];
                    a2 += wv * v[kx + 2]; a3 += wv * v[kx + 3];
                }
            }
        }
    }
    float4 r = make_float4(a0, a1, a2, a3);
    *(float4*)(out + ((long)(b * C2 + co)) * PP + p) = r;
}

// ---------------- pool from catb: poolb[b][opx48][ci] = avg of 2x2 catb pixels ------------
// Replaces avgpool_bf16 (56.6 MB fp32 read + LDS transpose): catb is already bf16 px-major,
// so pooling it is a 28.3 MB read with NO transpose. grid (432, B), 8 ci per thread.
__global__ __launch_bounds__(256) void pool_catb_kernel(
    const ushort_t* __restrict__ catb, ushort_t* __restrict__ poolb)
{
    int b = blockIdx.y;
    long i = (long)blockIdx.x * 256 + threadIdx.x;   // [0, 2304*48)
    int opx = (int)(i / 48), cg = (int)(i - (long)opx * 48);
    int oy = opx / 48, ox = opx - oy * 48;
    const ushort_t* base = catb + (long)b * PP * C2
                         + ((long)(2 * oy) * WW + 2 * ox) * C2 + cg * 8;
    uint4 A  = *(const uint4*)(base);
    uint4 Bv = *(const uint4*)(base + C2);
    uint4 Cv = *(const uint4*)(base + (long)WW * C2);
    uint4 Dv = *(const uint4*)(base + (long)WW * C2 + C2);
    const unsigned* au = (const unsigned*)&A;
    const unsigned* bu = (const unsigned*)&Bv;
    const unsigned* cu = (const unsigned*)&Cv;
    const unsigned* du = (const unsigned*)&Dv;
    ushort_t outv[8];
#pragma unroll
    for (int u = 0; u < 4; ++u) {
        float lo = 0.25f * (bflo(au[u]) + bflo(bu[u]) + bflo(cu[u]) + bflo(du[u]));
        float hi = 0.25f * (bfhi(au[u]) + bfhi(bu[u]) + bfhi(cu[u]) + bfhi(du[u]));
        outv[2 * u]     = f2bf(lo);
        outv[2 * u + 1] = f2bf(hi);
    }
    *(uint4*)(poolb + ((long)b * 2304 + opx) * C2 + cg * 8) = *(uint4*)outv;
}

// ---------------- packed weight prep: wpk[((tap*NG+cg)*24+chunk)*64 + n*2+q][8] -----------
template<int NG>
__global__ __launch_bounds__(256) void prep_wpk_kernel(
    const float* __restrict__ w, ushort_t* __restrict__ wpk, int coutv)
{
    int i = blockIdx.x * 256 + threadIdx.x;
    int j = i & 7;
    int q = (i >> 3) & 1;
    int n = (i >> 4) & 31;
    int r = i >> 9;
    int chunk = r % 24;
    int r2 = r / 24;
    int cg = r2 % NG;
    int tap = r2 / NG;
    int co = cg * 32 + n;
    int ci = chunk * 16 + q * 8 + j;
    wpk[i] = (co < coutv) ? f2bf(w[((long)co * 384 + ci) * 9 + tap]) : (ushort_t)0;
}

// ---------------- conv48 MFMA: valid 3x3 48->46, double-buffered input staging -----------
// cell stride 24 ushorts (48 B): b128 LDS reads/writes, bank-tiling {0,12,24,...} -> 0 conflicts
__global__ __launch_bounds__(256) void conv48_mfma_kernel(
    const ushort_t* __restrict__ poolb, const ushort_t* __restrict__ wpk,
    float* __restrict__ out)
{
    __shared__ __align__(16) ushort_t sB[2][288 * 24];
    int b = blockIdx.z;
    int co0 = blockIdx.y * 128;
    int cgb = blockIdx.y * 4;
    int y0 = blockIdx.x * 4;
    int t = threadIdx.x;
    int w = t >> 6, lane = t & 63;
    int n = lane & 31, q = lane >> 5;
    int wc = w & 1, wn = w >> 1;
    const uint4* wq = (const uint4*)wpk;

    int pidx[3], rr[3], ccx[3];
#pragma unroll
    for (int xg = 0; xg < 3; ++xg) {
        int p = (wn * 3 + xg) * 32 + n;
        int pc = min(p, 183);
        pidx[xg] = p;
        rr[xg] = pc / 46;
        ccx[xg] = pc - rr[xg] * 46;
    }

    floatx16 acc[2][3];
#pragma unroll
    for (int a = 0; a < 2; ++a)
#pragma unroll
        for (int xg = 0; xg < 3; ++xg) acc[a][xg] = (floatx16)(0.f);

    const ushort_t* poolb_b = poolb + (long)b * 2304 * C2;

    bool sok[2]; long gof[2]; int lof[2]; bool sval[2];
#pragma unroll
    for (int s = 0; s < 2; ++s) {
        int c = t + s * 256;
        sval[s] = (c < 288);
        int cc = min(c, 287);
        int r = cc / 48, col = cc - r * 48;
        int iy = y0 + r;
        sok[s] = (iy < 48);
        gof[s] = ((long)(min(iy, 47) * 48 + col)) * C2;
        lof[s] = cc * 24;
    }
    uint4 sv[2][2];

#define C48_ISSUE(mm)                                                        \
    {                                                                        \
        int ci0 = (mm) * 16;                                                 \
        _Pragma("unroll")                                                    \
        for (int s = 0; s < 2; ++s) {                                        \
            if (sval[s] && sok[s]) {                                         \
                const ushort_t* sp = poolb_b + gof[s] + ci0;                 \
                sv[s][0] = *(const uint4*)(sp);                              \
                sv[s][1] = *(const uint4*)(sp + 8);                          \
            } else {                                                         \
                sv[s][0] = make_uint4(0u,0u,0u,0u);                          \
                sv[s][1] = make_uint4(0u,0u,0u,0u);                          \
            }                                                                \
        }                                                                    \
    }
#define C48_COMMIT(buf)                                                      \
    {                                                                        \
        _Pragma("unroll")                                                    \
        for (int s = 0; s < 2; ++s) {                                        \
            if (sval[s]) {                                                   \
                ushort_t* d = sB[buf] + lof[s];                              \
                *(uint4*)(d + 0) = sv[s][0];                                 \
                *(uint4*)(d + 8) = sv[s][1];                                 \
            }                                                                \
        }                                                                    \
    }

    C48_ISSUE(0); C48_COMMIT(0);
    __syncthreads();

    for (int m = 0; m < 24; ++m) {
        int cur = m & 1;
        if (m < 23) C48_ISSUE(m + 1);
#pragma unroll
        for (int ky = 0; ky < 3; ++ky) {
            uint4 wv[6];
#pragma unroll
            for (int kx = 0; kx < 3; ++kx)
#pragma unroll
                for (int a = 0; a < 2; ++a)
                    wv[kx * 2 + a] = wq[(long)(((ky * 3 + kx) * 12 + cgb + wc * 2 + a) * 24 + m) * 64 + lane];
#pragma unroll
            for (int kx = 0; kx < 3; ++kx) {
                bf16x8 af[2], bfm[3];
#pragma unroll
                for (int a = 0; a < 2; ++a)
                    af[a] = __builtin_bit_cast(bf16x8, wv[kx * 2 + a]);
#pragma unroll
                for (int xg = 0; xg < 3; ++xg) {
                    int cell = (rr[xg] + ky) * 48 + ccx[xg] + kx;
                    uint4 bv = *(const uint4*)(sB[cur] + cell * 24 + q * 8);
                    bfm[xg] = __builtin_bit_cast(bf16x8, bv);
                }
#pragma unroll
                for (int a = 0; a < 2; ++a)
#pragma unroll
                    for (int xg = 0; xg < 3; ++xg)
                        acc[a][xg] = __builtin_amdgcn_mfma_f32_32x32x16_bf16(
                            af[a], bfm[xg], acc[a][xg], 0, 0, 0);
            }
        }
        if (m < 23) C48_COMMIT(cur ^ 1);
        __syncthreads();
    }

#pragma unroll
    for (int a = 0; a < 2; ++a) {
        int cobase = co0 + (wc * 2 + a) * 32;
#pragma unroll
        for (int xg = 0; xg < 3; ++xg) {
            int oy = y0 + rr[xg], ox = ccx[xg];
            if (pidx[xg] >= 184 || oy >= 46) continue;
#pragma unroll
            for (int r = 0; r < 16; ++r) {
                int row = (r & 3) + 8 * (r >> 2) + 4 * q;
                out[((long)(b * C2 + cobase + row)) * 2116 + oy * 46 + ox] = acc[a][xg][r];
            }
        }
    }
}

// ---------------- cvt_cat: catb[b][px][ci] bf16 from cat(q=qkv2[0:192], y) ----------------
__global__ __launch_bounds__(256) void cvt_cat_kernel(
    const float* __restrict__ qkv2, const float* __restrict__ y, ushort_t* __restrict__ catb)
{
    __shared__ __align__(16) ushort_t sT[64 * 392];
    int b = blockIdx.y;
    int px0 = blockIdx.x * 64;
    int t = threadIdx.x;
    for (int idx = t; idx < 384 * 64; idx += 256) {
        int ci = idx >> 6, px = idx & 63;
        const float* src = (ci < CC) ? qkv2 + ((long)(b * C2 + ci)) * PP
                                     : y + ((long)(b * CC + ci - CC)) * PP;
        sT[px * 392 + ci] = f2bf(src[px0 + px]);
    }
    __syncthreads();
    int px = t >> 2, qr = t & 3;
    ushort_t* dst = catb + ((long)b * PP + px0 + px) * C2 + qr * 96;
    const ushort_t* srcl = sT + px * 392 + qr * 96;
#pragma unroll
    for (int k = 0; k < 96; k += 8)
        *(uint4*)(dst + k) = *(const uint4*)(srcl + k);
}

// ---------------- conv96 MFMA v5: 2-deep register staging ---------------------------------
// grid (96, 3, B); block 256 (4 waves). LDS: 3 rows x 98 cols, double-buffered.
// v5 = v4 + TWO register staging buffers (svA/svB): tile m+2 issues during step m, commits
// at end of step m+1 -> staging cover grows from one compute phase (~500cy) to ~1.5 phases,
// enough for the ~33% of staging loads that miss L2 (FETCH 86/260 MB) and cost ~900cy.
// Manual x2 loop unroll keeps buffer selection static (no dynamic indexing).
__global__ __launch_bounds__(256) void conv96_mfma_kernel(
    const ushort_t* __restrict__ catb, const ushort_t* __restrict__ wpk,
    const float* __restrict__ qkv2, const float* __restrict__ yy,
    const float* __restrict__ k2out, ushort_t* __restrict__ scb)
{
    __shared__ __align__(16) ushort_t sB[2][294 * 24];
    int b = blockIdx.z;
    int co0 = blockIdx.y * 128;
    int cgb = blockIdx.y * 4;
    int bx = blockIdx.x;
    int yl = (bx & 7) * 12 + (bx >> 3);   // XCD stripe swizzle (bijective on [0,96))
    int t = threadIdx.x;
    int w = t >> 6, lane = t & 63;
    int n = lane & 31, q = lane >> 5;
    const uint4* wq = (const uint4*)wpk;

    floatx16 acc[3];
#pragma unroll
    for (int xg = 0; xg < 3; ++xg) acc[xg] = (floatx16)(0.f);

    const ushort_t* catb_b = catb + (long)b * PP * C2;

    // staging geometry: 294 cells = 3 rows (yl-1..yl+1) x 98 cols (x=-1..96)
    bool sok[2]; long gof[2]; int lof[2]; bool sval[2];
#pragma unroll
    for (int s = 0; s < 2; ++s) {
        int c = t + s * 256;
        sval[s] = (c < 294);
        int cc = min(c, 293);
        int r = cc / 98, col = cc - r * 98;
        int iy = yl - 1 + r, ix = col - 1;
        sok[s] = (iy >= 0 && iy < HH && ix >= 0 && ix < WW);
        gof[s] = ((long)(min(max(iy, 0), HH - 1) * WW + min(max(ix, 0), WW - 1))) * C2;
        lof[s] = cc * 24;
    }
    uint4 svA[2][2], svB[2][2];

#define C96_ISSUE(SV, mm)                                                    \
    {                                                                        \
        int ci0 = (mm) * 16;                                                 \
        _Pragma("unroll")                                                    \
        for (int s = 0; s < 2; ++s) {                                        \
            if (sval[s] && sok[s]) {                                         \
                const ushort_t* sp = catb_b + gof[s] + ci0;                  \
                SV[s][0] = *(const uint4*)(sp);                              \
                SV[s][1] = *(const uint4*)(sp + 8);                          \
            } else {                                                         \
                SV[s][0] = make_uint4(0u,0u,0u,0u);                          \
                SV[s][1] = make_uint4(0u,0u,0u,0u);                          \
            }                                                                \
        }                                                                    \
    }
#define C96_COMMIT(SV, buf)                                                  \
    {                                                                        \
        _Pragma("unroll")                                                    \
        for (int s = 0; s < 2; ++s) {                                        \
            if (sval[s]) {                                                   \
                ushort_t* d = sB[buf] + lof[s];                              \
                *(uint4*)(d + 0) = SV[s][0];                                 \
                *(uint4*)(d + 8) = SV[s][1];                                 \
            }                                                                \
        }                                                                    \
    }
// one K-step: weights FIRST (vmcnt FIFO: MFMA's weight-wait leaves younger staging loads
// in flight), then the 2-ahead ISSUE, then MFMA, then commit of tile MM+1.
#define C96_STEP(CUR, MM, SVI, SVC, DOISSUE)                                 \
    {                                                                        \
        uint4 wv[9];                                                         \
        _Pragma("unroll")                                                    \
        for (int tap = 0; tap < 9; ++tap)                                    \
            wv[tap] = wq[(long)((tap * 12 + cgb + w) * 24 + (MM)) * 64 + lane]; \
        if (DOISSUE) C96_ISSUE(SVI, (MM) + 2);                               \
        _Pragma("unroll")                                                    \
        for (int ky = 0; ky < 3; ++ky) {                                     \
            _Pragma("unroll")                                                \
            for (int kx = 0; kx < 3; ++kx) {                                 \
                bf16x8 af = __builtin_bit_cast(bf16x8, wv[ky * 3 + kx]);     \
                _Pragma("unroll")                                            \
                for (int xg = 0; xg < 3; ++xg) {                             \
                    int cell = ky * 98 + xg * 32 + n + kx;                   \
                    uint4 bv = *(const uint4*)(sB[CUR] + cell * 24 + q * 8); \
                    bf16x8 bfm = __builtin_bit_cast(bf16x8, bv);             \
                    acc[xg] = __builtin_amdgcn_mfma_f32_32x32x16_bf16(       \
                        af, bfm, acc[xg], 0, 0, 0);                          \
                }                                                            \
            }                                                                \
        }                                                                    \
        if ((MM) < 23) C96_COMMIT(SVC, (CUR) ^ 1);                           \
        __syncthreads();                                                     \
    }

    C96_ISSUE(svA, 0); C96_COMMIT(svA, 0);
    C96_ISSUE(svB, 1);
    __syncthreads();

    for (int m = 0; m < 24; m += 2) {
        C96_STEP(0, m,     svA, svB, (m < 22));
        C96_STEP(1, m + 1, svB, svA, (m + 1 < 22));
    }

    // epilogue: scb[b][px][co] = bf16( acc * sigmoid(cat + nearest(k2out)) )
    int iy46 = (yl * 46) / 96;
    int cobase = co0 + w * 32;
#pragma unroll
    for (int xg = 0; xg < 3; ++xg) {
        int x = xg * 32 + n;
        int ix46 = (x * 46) / 96;
        ushort_t* dst = scb + ((long)(b * PP + yl * WW + x)) * C2;
#pragma unroll
        for (int g = 0; g < 4; ++g) {
            int cog = cobase + 8 * g + 4 * q;
            ushort_t pk[4];
#pragma unroll
            for (int j = 0; j < 4; ++j) {
                int co = cog + j;
                const float* gsrc = (co < CC) ? qkv2 + ((long)(b * C2 + co)) * PP
                                              : yy + ((long)(b * CC + co - CC)) * PP;
                float kv = k2out[((long)(b * C2 + co)) * 2116 + iy46 * 46 + ix46];
                float gg = gsrc[yl * WW + x] + kv;
                pk[j] = f2bf(acc[xg][4 * g + j] * sigmoidf_(gg));
            }
            *(uint2*)(dst + cog) = *(uint2*)pk;
        }
    }
}

// ---------------- k4 MFMA: offs = conv3x3(scb), M=32 pad, double-buffered ----------------
__global__ __launch_bounds__(384) void k4_mfma_kernel(
    const ushort_t* __restrict__ scb, const ushort_t* __restrict__ wpk4,
    float* __restrict__ out)
{
    __shared__ __align__(16) ushort_t sB[2][392 * 24];
    int b = blockIdx.y;
    int y0 = blockIdx.x * 2;
    int t = threadIdx.x;
    int w = t / 64, lane = t & 63;
    int n = lane & 31, q = lane >> 5;
    int wr = w / 3, xg = w - wr * 3;
    const uint4* wq = (const uint4*)wpk4;

    floatx16 acc = (floatx16)(0.f);
    const ushort_t* scb_b = scb + (long)b * PP * C2;

    bool sok[2]; long gof[2]; int lof[2]; bool sval[2];
#pragma unroll
    for (int s = 0; s < 2; ++s) {
        int c = t + s * 384;
        sval[s] = (c < 392);
        int cc = min(c, 391);
        int r = cc / 98, col = cc - r * 98;
        int iy = y0 - 1 + r, ix = col - 1;
        sok[s] = (iy >= 0 && iy < HH && ix >= 0 && ix < WW);
        gof[s] = ((long)(min(max(iy, 0), HH - 1) * WW + min(max(ix, 0), WW - 1))) * C2;
        lof[s] = cc * 24;
    }
    uint4 sv[2][2];

#define K4_ISSUE(mm)                                                         \
    {                                                                        \
        int ci0 = (mm) * 16;                                                 \
        _Pragma("unroll")                                                    \
        for (int s = 0; s < 2; ++s) {                                        \
            if (sval[s] && sok[s]) {                                         \
                const ushort_t* sp = scb_b + gof[s] + ci0;                   \
                sv[s][0] = *(const uint4*)(sp);                              \
                sv[s][1] = *(const uint4*)(sp + 8);                          \
            } else {                                                         \
                sv[s][0] = make_uint4(0u,0u,0u,0u);                          \
                sv[s][1] = make_uint4(0u,0u,0u,0u);                          \
            }                                                                \
        }                                                                    \
    }
#define K4_COMMIT(buf)                                                       \
    {                                                                        \
        _Pragma("unroll")                                                    \
        for (int s = 0; s < 2; ++s) {                                        \
            if (sval[s]) {                                                   \
                ushort_t* d = sB[buf] + lof[s];                              \
                *(uint4*)(d + 0) = sv[s][0];                                 \
                *(uint4*)(d + 8) = sv[s][1];                                 \
            }                                                                \
        }                                                                    \
    }

    K4_ISSUE(0); K4_COMMIT(0);
    __syncthreads();

    for (int m = 0; m < 24; ++m) {
        int cur = m & 1;
        if (m < 23) K4_ISSUE(m + 1);
#pragma unroll
        for (int ky = 0; ky < 3; ++ky) {
            uint4 wv[3];
#pragma unroll
            for (int kx = 0; kx < 3; ++kx)
                wv[kx] = wq[(long)(((ky * 3 + kx) * 24) + m) * 64 + lane];
#pragma unroll
            for (int kx = 0; kx < 3; ++kx) {
                bf16x8 af = __builtin_bit_cast(bf16x8, wv[kx]);
                int col = xg * 32 + n + kx;
                uint4 bv = *(const uint4*)(sB[cur] + ((wr + ky) * 98 + col) * 24 + q * 8);
                bf16x8 bf = __builtin_bit_cast(bf16x8, bv);
                acc = __builtin_amdgcn_mfma_f32_32x32x16_bf16(af, bf, acc, 0, 0, 0);
            }
        }
        if (m < 23) K4_COMMIT(cur ^ 1);
        __syncthreads();
    }

    int yl = y0 + wr;
    int x = xg * 32 + n;
#pragma unroll
    for (int r = 0; r < 16; ++r) {
        int row = (r & 3) + 8 * (r >> 2) + 4 * q;
        if (row < 18)
            out[((long)(b * 18 + row)) * PP + yl * WW + x] = acc[r];
    }
}

// ---------------- deformable conv, bf16 LDS tile from catb -------------------------------
// EXACT r3 body+geometry (150 us plateau). Closed: schedule edits (R4, R5) and geometry
// edits (R8) all regressed; runtime does not respond to added waves or reordering.
#define DW 22
__global__ __launch_bounds__(256) void deform_kernel(
    const ushort_t* __restrict__ catb, const float* __restrict__ offs,
    const float* __restrict__ w, const float* __restrict__ bias, float* __restrict__ out)
{
    __shared__ __align__(16) ushort_t sQ[DW * DW * 24];
    int b = blockIdx.z, g = blockIdx.y;
    int tile = blockIdx.x;
    int ty0 = (tile / 6) * 16, tx0 = (tile % 6) * 16;
    int wy0 = ty0 - 3, wx0 = tx0 - 3;
    int t = threadIdx.x;
    int oy = ty0 + (t >> 4), ox = tx0 + (t & 15);
    int p = oy * WW + ox;

    const ushort_t* cb = catb + (long)b * PP * C2 + g * 24;
    for (int idx = t; idx < 484 * 3; idx += 256) {
        int cell = idx / 3, part = idx - cell * 3;
        int sy = cell / DW, sx = cell - sy * DW;
        int syc = min(max(wy0 + sy, 0), HH - 1);
        int sxc = min(max(wx0 + sx, 0), WW - 1);
        uint4 v = *(const uint4*)(cb + ((long)(syc * WW + sxc)) * C2 + part * 8);
        *(uint4*)(sQ + cell * 24 + part * 8) = v;
    }
    __syncthreads();

    const float* ob = offs + (long)b * 18 * PP;
    float acc[24];
#pragma unroll
    for (int o = 0; o < 24; ++o) acc[o] = 0.f;

    for (int k = 0; k < 9; ++k) {
        float dy = ob[(2 * k) * PP + p];
        float dx = ob[(2 * k + 1) * PP + p];
        float mk = sigmoidf_(ob[k * PP + p]);
        float py = dy + (float)(oy - 1 + k / 3);
        float px = dx + (float)(ox - 1 + (k % 3));
        float fy = floorf(py), fx = floorf(px);
        int y0 = (int)fy, x0 = (int)fx;
        float ly = py - fy, lx = px - fx;
        float w00 = (1.f - ly) * (1.f - lx), w01 = (1.f - ly) * lx;
        float w10 = ly * (1.f - lx), w11 = ly * lx;
        bool vy0 = (y0 >= 0 && y0 <= HH - 1), vy1 = (y0 + 1 <= HH - 1) && (y0 + 1 >= 0);
        bool vx0 = (x0 >= 0 && x0 <= WW - 1), vx1 = (x0 + 1 <= WW - 1) && (x0 + 1 >= 0);
        w00 = (vy0 && vx0) ? w00 * mk : 0.f;
        w01 = (vy0 && vx1) ? w01 * mk : 0.f;
        w10 = (vy1 && vx0) ? w10 * mk : 0.f;
        w11 = (vy1 && vx1) ? w11 * mk : 0.f;
        float vals[24];
        bool inwin = (y0 >= wy0) && (y0 - wy0 <= DW - 2) && (x0 >= wx0) && (x0 - wx0 <= DW - 2);
        if (inwin) {
            int c00 = (y0 - wy0) * DW + (x0 - wx0);
            const ushort_t* s00 = sQ + c00 * 24;
#pragma unroll
            for (int part = 0; part < 3; ++part) {
                uint4 A = *(const uint4*)(s00 + part * 8);
                uint4 Bv = *(const uint4*)(s00 + 24 + part * 8);
                uint4 Cv = *(const uint4*)(s00 + DW * 24 + part * 8);
                uint4 Dv = *(const uint4*)(s00 + DW * 24 + 24 + part * 8);
                const unsigned* au = (const unsigned*)&A;
                const unsigned* bu = (const unsigned*)&Bv;
                const unsigned* cu = (const unsigned*)&Cv;
                const unsigned* du = (const unsigned*)&Dv;
#pragma unroll
                for (int u = 0; u < 4; ++u) {
                    int ci = part * 8 + u * 2;
                    vals[ci]     = w00 * bflo(au[u]) + w01 * bflo(bu[u])
                                 + w10 * bflo(cu[u]) + w11 * bflo(du[u]);
                    vals[ci + 1] = w00 * bfhi(au[u]) + w01 * bfhi(bu[u])
                                 + w10 * bfhi(cu[u]) + w11 * bfhi(du[u]);
                }
            }
        } else {
            int y0c = min(max(y0, 0), HH - 1), y1c = min(max(y0 + 1, 0), HH - 1);
            int x0c = min(max(x0, 0), WW - 1), x1c = min(max(x0 + 1, 0), WW - 1);
            const ushort_t* p00 = cb + ((long)(y0c * WW + x0c)) * C2;
            const ushort_t* p01 = cb + ((long)(y0c * WW + x1c)) * C2;
            const ushort_t* p10 = cb + ((long)(y1c * WW + x0c)) * C2;
            const ushort_t* p11 = cb + ((long)(y1c * WW + x1c)) * C2;
#pragma unroll
            for (int part = 0; part < 3; ++part) {
                uint4 A = *(const uint4*)(p00 + part * 8);
                uint4 Bv = *(const uint4*)(p01 + part * 8);
                uint4 Cv = *(const uint4*)(p10 + part * 8);
                uint4 Dv = *(const uint4*)(p11 + part * 8);
                const unsigned* au = (const unsigned*)&A;
                const unsigned* bu = (const unsigned*)&Bv;
                const unsigned* cu = (const unsigned*)&Cv;
                const unsigned* du = (const unsigned*)&Dv;
#pragma unroll
                for (int u = 0; u < 4; ++u) {
                    int ci = part * 8 + u * 2;
                    vals[ci]     = w00 * bflo(au[u]) + w01 * bflo(bu[u])
                                 + w10 * bflo(cu[u]) + w11 * bflo(du[u]);
                    vals[ci + 1] = w00 * bfhi(au[u]) + w01 * bfhi(bu[u])
                                 + w10 * bfhi(cu[u]) + w11 * bfhi(du[u]);
                }
            }
        }
        const float* wg = w + (long)g * 24 * 216 + k;
#pragma unroll
        for (int o = 0; o < 24; ++o) {
            const float* wr = wg + (long)o * 216;
            float s = acc[o];
#pragma unroll
            for (int ci = 0; ci < 24; ++ci) s += wr[ci * 9] * vals[ci];
            acc[o] = s;
        }
    }
#pragma unroll
    for (int o = 0; o < 24; ++o)
        out[((long)(b * CC + g * 24 + o)) * PP + p] = acc[o] + bias[g * 24 + o];
}

// ---------------- attention stage A: partial 24x24 dot blocks + fused norm partials ------
__global__ __launch_bounds__(192) void attn_part_kernel(
    const float* __restrict__ q, const float* __restrict__ kb,
    float* __restrict__ part, float* __restrict__ normp)
{
    __shared__ __align__(16) float sQ[24 * 260];   // 260-pad: row starts at bank 4*r -> 0 conflicts
    __shared__ __align__(16) float sK[24 * 260];
    __shared__ float sS[192];
    int slice = blockIdx.x, h = blockIdx.y, b = blockIdx.z;
    int t = threadIdx.x;
    int w = t >> 6, lane = t & 63;
    int a_ = lane >> 3, b_ = lane & 7;
    const float* qbase = q + ((long)(b * C2) + h * 24) * PP;
    const float* kbase = kb + ((long)(b * CC) + h * 24) * PP;

    // sumsq assignment: row rr = t/4 (0..23 = q rows, 24..47 = k rows), quarter qq = t%4
    int rr = t >> 2, qq = t & 3;
    const float* srow = (rr < 24) ? (sQ + rr * 260) : (sK + (rr - 24) * 260);
    srow += qq * 64;
    float ssq = 0.f;

    float4 acc[3];
#pragma unroll
    for (int i = 0; i < 3; ++i) acc[i] = make_float4(0.f, 0.f, 0.f, 0.f);

    for (int sc = 0; sc < 2; ++sc) {
        int n0 = slice * 512 + sc * 256;
        for (int i = t; i < 1536; i += 192) {
            int r = i >> 6, c4 = i & 63;
            *(float4*)(sQ + r * 260 + c4 * 4) =
                *(const float4*)(qbase + (long)r * PP + n0 + c4 * 4);
            *(float4*)(sK + r * 260 + c4 * 4) =
                *(const float4*)(kbase + (long)r * PP + n0 + c4 * 4);
        }
        __syncthreads();
        // norm partial: 16 float4 from this thread's row-quarter
#pragma unroll 4
        for (int p4 = 0; p4 < 16; ++p4) {
            float4 v = *(const float4*)(srow + p4 * 4);
            ssq += v.x * v.x + v.y * v.y + v.z * v.z + v.w * v.w;
        }
#pragma unroll
        for (int t3 = 0; t3 < 3; ++t3) {
            int tile = w * 3 + t3;
            const float* qr = sQ + ((tile / 3) * 8 + a_) * 260;
            const float* kr = sK + ((tile % 3) * 8 + b_) * 260;
            float4 s = acc[t3];
#pragma unroll 8
            for (int p4 = 0; p4 < 64; ++p4) {
                float4 qv = *(const float4*)(qr + p4 * 4);
                float4 kv = *(const float4*)(kr + p4 * 4);
                s.x += qv.x * kv.x; s.y += qv.y * kv.y;
                s.z += qv.z * kv.z; s.w += qv.w * kv.w;
            }
            acc[t3] = s;
        }
        __syncthreads();
    }
    // reduce 4 quarters per row and emit norm partials
    sS[t] = ssq;
    __syncthreads();
    if (t < 48) {
        float tot = sS[4 * t] + sS[4 * t + 1] + sS[4 * t + 2] + sS[4 * t + 3];
        normp[(((long)(b * 8 + h) * 18) + slice) * 48 + t] = tot;
    }
#pragma unroll
    for (int t3 = 0; t3 < 3; ++t3) {
        int tile = w * 3 + t3;
        int c = (tile / 3) * 8 + a_;
        int d = (tile % 3) * 8 + b_;
        float s = acc[t3].x + acc[t3].y + acc[t3].z + acc[t3].w;
        part[(((long)(b * 8 + h) * 18) + slice) * 576 + c * 24 + d] = s;
    }
}

// ---------------- attention stage B: reduce slices + norms + normalize + softmax ---------
__global__ __launch_bounds__(256) void attn_reduce_kernel(
    const float* __restrict__ part, const float* __restrict__ normp,
    const float* __restrict__ temp, float* __restrict__ attn)
{
    __shared__ float L[576];
    __shared__ float nrm[48];
    __shared__ float rmx[24], rsm[24];
    int h = blockIdx.x, b = blockIdx.y;
    int t = threadIdx.x;
    const float* pb = part + ((long)(b * 8 + h) * 18) * 576;
    const float* npb = normp + ((long)(b * 8 + h) * 18) * 48;
    float tmp = temp[h];
    if (t < 48) {
        float s = 0.f;
#pragma unroll
        for (int sl = 0; sl < 18; ++sl) s += npb[sl * 48 + t];
        nrm[t] = fmaxf(sqrtf(s), 1e-12f);
    }
    __syncthreads();
    for (int pid = t; pid < 576; pid += 256) {
        float s = 0.f;
#pragma unroll
        for (int sl = 0; sl < 18; ++sl) s += pb[sl * 576 + pid];
        int c = pid / 24, d = pid - c * 24;
        L[pid] = s / (nrm[c] * nrm[24 + d]) * tmp;
    }
    __syncthreads();
    if (t < 24) {
        float mx = -3.4e38f;
#pragma unroll
        for (int j = 0; j < 24; ++j) mx = fmaxf(mx, L[t * 24 + j]);
        float sm = 0.f;
#pragma unroll
        for (int j = 0; j < 24; ++j) sm += expf(L[t * 24 + j] - mx);
        rmx[t] = mx; rsm[t] = 1.f / sm;
    }
    __syncthreads();
    for (int pid = t; pid < 576; pid += 256) {
        int c = pid / 24;
        attn[((long)(b * 8 + h)) * 576 + pid] = expf(L[pid] - rmx[c]) * rsm[c];
    }
}

// ---------------- attn @ v: block per (slice, h, b); v read ONCE ------------------------
__global__ __launch_bounds__(128) void attn_apply_kernel(
    const float* __restrict__ attn, const float* __restrict__ qkv2, float* __restrict__ out)
{
    __shared__ float sA[576];
    int slice = blockIdx.x, h = blockIdx.y, b = blockIdx.z;
    int t = threadIdx.x;
    for (int i = t; i < 576; i += 128)
        sA[i] = attn[((long)(b * 8 + h)) * 576 + i];
    __syncthreads();
    int n = slice * 512 + t * 4;
    const float* vbase = qkv2 + ((long)(b * C2) + CC + h * 24) * PP;
    float4 acc[24];
#pragma unroll
    for (int c = 0; c < 24; ++c) acc[c] = make_float4(0.f, 0.f, 0.f, 0.f);
#pragma unroll 4
    for (int d = 0; d < 24; ++d) {
        float4 vv = *(const float4*)(vbase + (long)d * PP + n);
#pragma unroll
        for (int c = 0; c < 24; ++c) {
            float a = sA[c * 24 + d];
            acc[c].x += a * vv.x; acc[c].y += a * vv.y;
            acc[c].z += a * vv.z; acc[c].w += a * vv.w;
        }
    }
#pragma unroll
    for (int c = 0; c < 24; ++c)
        *(float4*)(out + ((long)(b * CC + h * 24 + c)) * PP + n) = acc[c];
}

// =========================================================================================
extern "C" void kernel_launch(void* const* d_in, const int* in_sizes, int n_in,
                              void* d_out, int out_size, void* d_ws, size_t ws_size,
                              hipStream_t stream)
{
    const float* x          = (const float*)d_in[0];
    const float* y          = (const float*)d_in[1];
    const float* temp       = (const float*)d_in[2];
    const float* qkv_w      = (const float*)d_in[3];
    const float* qkv_conv_w = (const float*)d_in[4];
    const float* proj_w     = (const float*)d_in[5];
    const float* k2_w       = (const float*)d_in[6];
    const float* k3_w       = (const float*)d_in[7];
    const float* k4_w       = (const float*)d_in[8];
    const float* deform_w   = (const float*)d_in[9];
    const float* deform_b   = (const float*)d_in[10];
    const float* pw_w       = (const float*)d_in[11];
    const float* pw_b       = (const float*)d_in[12];

    float* ws = (float*)d_ws;
    const long SZ_FULL = (long)BB * C2 * PP;     // 14,155,776
    const long SZ_HALF = (long)BB * CC * PP;     //  7,077,888

    float* bufA   = ws;
    float* qkv2   = ws + SZ_FULL;
    float* k2out  = ws + 2 * SZ_FULL;
    float* ovl    = k2out + (long)BB * C2 * 2116;
    ushort_t* catb  = (ushort_t*)ovl;
    ushort_t* wbuf = (ushort_t*)(ovl + SZ_HALF);
    ushort_t* wb4  = (ushort_t*)(ovl + SZ_HALF + 663552);
    float* offs   = ovl + SZ_HALF + 663552 + 55296;
    float* attnm  = offs + (long)BB * 18 * PP;

    float* qkv1    = bufA;
    ushort_t* wb2  = (ushort_t*)bufA;
    ushort_t* poolb = (ushort_t*)(bufA + 700000);       // after wb2 (663,552 floats); dead before scb
    ushort_t* scb  = (ushort_t*)bufA;
    float* kbuf    = bufA;
    float* feat    = bufA + SZ_HALF;
    float* attnout = bufA + SZ_HALF;
    float* attnp   = bufA + SZ_HALF;                    // partials in dead feat space
    float* normp   = attnp + (long)BB * 8 * 18 * 576;   // norm partials right after

    // 1. qkv = conv1x1(x, qkv_w)
    conv1x1_kernel<CC, false, false><<<dim3(9, 24, BB), 256, 0, stream>>>(
        x, qkv_w, nullptr, qkv1, (long)CC * PP, (long)C2 * PP);
    // 2. qkv = grouped 3x3 (groups=192), 4 px/thread
    dwconv_kernel<<<dim3(9, C2, BB), 256, 0, stream>>>(qkv1, qkv_conv_w, qkv2);
    // 3. catb = bf16 transposed cat (moved up; qkv1 dead after disp 2)
    cvt_cat_kernel<<<dim3(144, BB), 256, 0, stream>>>(qkv2, y, catb);
    // 4. wb2 = packed k2 weight fragments (into dead qkv1 space)
    prep_wpk_kernel<12><<<dim3(9 * 12 * 24 * 64 * 8 / 256), 256, 0, stream>>>(k2_w, wb2, 384);
    // 5. poolb = 2x2 avg of catb (28.3 MB read, no transpose; replaces 56.6 MB avgpool)
    pool_catb_kernel<<<dim3(432, BB), 256, 0, stream>>>(catb, poolb);
    // 6. k2out = conv3x3 valid (48->46)  -- MFMA, double-buffered, b128 LDS
    conv48_mfma_kernel<<<dim3(12, 3, BB), 256, 0, stream>>>(poolb, wb2, k2out);
    // 7. packed weight preps: k3 and k4
    prep_wpk_kernel<12><<<dim3(9 * 12 * 24 * 64 * 8 / 256), 256, 0, stream>>>(k3_w, wbuf, 384);
    prep_wpk_kernel<1><<<dim3(9 * 1 * 24 * 64 * 8 / 256), 256, 0, stream>>>(k4_w, wb4, 18);
    // 8. scb = bf16 px-major gated conv  -- MFMA v5: 2-deep register staging
    conv96_mfma_kernel<<<dim3(96, 3, BB), 256, 0, stream>>>(
        catb, wbuf, qkv2, y, k2out, scb);
    // 9. offset = conv3x3(scb, k4)  -- MFMA, double-buffered, b128 LDS
    k4_mfma_kernel<<<dim3(48, BB), 384, 0, stream>>>(scb, wb4, offs);
    // 10. feat = deform_conv (exact r3 body, closed)
    deform_kernel<<<dim3(36, 8, BB), 256, 0, stream>>>(catb, offs, deform_w, deform_b, feat);
    // 11. k = conv1x1(relu(feat), pw_w) + pw_b
    conv1x1_kernel<CC, true, true><<<dim3(9, 12, BB), 256, 0, stream>>>(
        feat, pw_w, pw_b, kbuf, (long)CC * PP, (long)CC * PP);
    // 12. attn partial dots + fused norm partials (q,k read once; norm_kernel eliminated)
    attn_part_kernel<<<dim3(18, 8, BB), 192, 0, stream>>>(qkv2, kbuf, attnp, normp);
    // 13. reduce + norms + normalize + softmax
    attn_reduce_kernel<<<dim3(8, BB), 256, 0, stream>>>(attnp, normp, temp, attnm);
    // 14. attnout = attn @ v (v read once)
    attn_apply_kernel<<<dim3(18, 8, BB), 128, 0, stream>>>(attnm, qkv2, attnout);
    // 15. out = conv1x1(attnout, proj_w)
    conv1x1_kernel<CC, false, false><<<dim3(9, 12, BB), 256, 0, stream>>>(
        attnout, proj_w, nullptr, (float*)d_out, (long)CC * PP, (long)CC * PP);
}